// Round 9
// baseline (233.069 us; speedup 1.0000x reference)
//
#include <hip/hip_runtime.h>
#include <math.h>

#define HD 128
#define NNODE 8192
#define KNBR 8
#define NHS ((size_t)NNODE*(size_t)HD)

#define EPSF 1e-6f
#define PMX 0.9999f
#define ATHC (1.0f-1e-5f)
#define TANC 1.47079f

typedef unsigned short u16;
typedef unsigned int u32;
typedef _Float16 f16;
typedef __attribute__((ext_vector_type(4))) float f32x4;
typedef __attribute__((ext_vector_type(2))) float f32x2;
typedef __attribute__((ext_vector_type(2))) _Float16 f16x2;
typedef __attribute__((ext_vector_type(4))) _Float16 f16x4;
typedef __attribute__((ext_vector_type(8))) _Float16 f16x8;

// ---------- fast hardware math ----------
static __device__ __forceinline__ float frcp(float x){ return __builtin_amdgcn_rcpf(x); }
static __device__ __forceinline__ float fdiv(float a,float b){ return a*__builtin_amdgcn_rcpf(b); }
static __device__ __forceinline__ float fsqrt(float x){ return __builtin_amdgcn_sqrtf(x); }
static __device__ __forceinline__ float fexp(float x){ return __builtin_amdgcn_exp2f(x*1.4426950408889634f); }
static __device__ __forceinline__ float flog(float x){ return __builtin_amdgcn_logf(x)*0.6931471805599453f; }
static __device__ __forceinline__ float ftanh(float x){
  float ax = fabsf(x);
  float e = fexp(-2.0f*ax);
  float t = (1.0f-e)*frcp(1.0f+e);
  return copysignf(t,x);
}
static __device__ __forceinline__ float fatanh(float x){
  x = fminf(fmaxf(x,-ATHC),ATHC);
  return 0.5f*flog((1.0f+x)*frcp(1.0f-x));
}
static __device__ __forceinline__ float fatan(float x){
  float ax = fabsf(x);
  bool inv = ax > 1.0f;
  float t = inv ? frcp(ax) : ax;
  float t2 = t*t;
  float p = -0.0117212f;
  p = p*t2 + 0.05265332f;
  p = p*t2 - 0.11643287f;
  p = p*t2 + 0.19354346f;
  p = p*t2 - 0.33262347f;
  p = p*t2 + 0.99997726f;
  float r = t*p;
  r = inv ? 1.5707963267948966f - r : r;
  return copysignf(r,x);
}
static __device__ __forceinline__ float ftan(float x){
  x = fminf(fmaxf(x,-TANC),TANC);
  float r = x*0.15915494309189535f;
  float s = __builtin_amdgcn_sinf(r);
  float c = __builtin_amdgcn_cosf(r);
  return s*frcp(c);
}
static __device__ __forceinline__ float sigm(float x){ return frcp(1.0f+fexp(-x)); }
static __device__ __forceinline__ float safeden(float d){
  return d>=0.0f ? fmaxf(d,EPSF) : fminf(d,-EPSF);
}

static __device__ __forceinline__ float wred(float v){
#pragma unroll
  for(int m=32;m;m>>=1) v += __shfl_xor(v,m,64);
  return v;
}
// reduce across lanes {x, x+16, x+32, x+48} (row-group in transposed GEMM layout)
static __device__ __forceinline__ float qred(float v){
  v += __shfl_xor(v,16,64);
  v += __shfl_xor(v,32,64);
  return v;
}

// ---------- f16 helpers ----------
static __device__ __forceinline__ f32x2 ldh2(const u16* p){
  f16x2 v = *(const f16x2*)p;
  return (f32x2){(float)v[0], (float)v[1]};
}
static __device__ __forceinline__ void sth2(u16* p, float a, float b){
  *(f16x2*)p = (f16x2){(f16)a, (f16)b};
}

// ---------------- workspace layout ----------------
// planes 0-8:  f16 A inputs (k_pre); planes 0-6 later reused for f16 Y planes (B-GEMM out)
// planes 9-17: f16 gemmA outputs S1..S3,F1..F3,Q1..Q3; 9-11 later overwritten by f16 LP/LS/LE,
//              12-14 later overwritten by f16 C1o..C3o
// planes 18-20: f16 XP,XS,XE
// planes 21-26: f16 consumer-grouped gather planes:
//   PKP @21, PKS @22, PKE @23: [node][64] f16x2 ; PKV4 @24: [node][64] f16x4 ; PKV2 @26: [node][64] f16x2
// SCOFF: SC4[node] = {y2p,y2s,d1,d2} f32, then c1n2 @+32768, c2n2 @+40960
#define SCOFF (27*NHS)
#define WOFF  (27*NHS + 49152)
#define NW    114688

// ---------------- kernel 1: weight convert + per-row pre-transforms (fused) ----------------
__global__ __launch_bounds__(256) void k_pre(
    const float* __restrict__ x, const float* __restrict__ h1,
    const float* __restrict__ h2, const float* __restrict__ c1,
    const float* __restrict__ c2, const float* __restrict__ h3,
    const float* __restrict__ c3,
    const float* __restrict__ Wq, const float* __restrict__ Wc,
    const float* __restrict__ Uf, const float* __restrict__ Up,
    const float* __restrict__ Uiou, float* __restrict__ ws)
{
  if(blockIdx.x >= 2048){
    // ---- weight f16 convert ----
    u16* WH = (u16*)(ws + WOFF);
    int idx0 = ((blockIdx.x-2048)*256 + threadIdx.x)*4;
#pragma unroll
    for(int q=0;q<4;q+=2){
      int idx = idx0 + q;
      float v0, v1;
      if(idx < 16384)      { v0=Wq[idx]; v1=Wq[idx+1]; }
      else if(idx < 32768) { v0=Wc[idx-16384]; v1=Wc[idx-16383]; }
      else if(idx < 49152) { v0=Uf[idx-32768]; v1=Uf[idx-32767]; }
      else if(idx < 65536) { v0=Up[idx-49152]; v1=Up[idx-49151]; }
      else                 { v0=Uiou[idx-65536]; v1=Uiou[idx-65535]; }
      sth2(&WH[idx], v0, v1);
    }
    return;
  }
  int row = blockIdx.x*4 + (threadIdx.x>>6);
  int l = threadIdx.x & 63;
  size_t i0 = (size_t)row*HD + 2*l;
#define LD2(p) (*(const f32x2*)&p[i0])
  f32x2 xv = LD2(x);
  f32x2 h1v = LD2(h1), h2v = LD2(h2), h3v = LD2(h3);
  f32x2 c1v = LD2(c1), c2v = LD2(c2), c3v = LD2(c3);
#undef LD2
  float xa=xv[0], xb=xv[1];
  float h1a=h1v[0], h1b=h1v[1];
  float h2a=h2v[0], h2b=h2v[1];
  float c1a=c1v[0], c1b=c1v[1];
  float c2a=c2v[0], c2b=c2v[1];
  float h3a=h3v[0], h3b=h3v[1];
  float c3a=c3v[0], c3b=c3v[1];
  float xsq = wred(xa*xa+xb*xb);
  float h1sq = wred(h1a*h1a+h1b*h1b);
  float h2sq = wred(h2a*h2a+h2b*h2b);
  float c1sq = wred(c1a*c1a+c1b*c1b);
  float c2sq = wred(c2a*c2a+c2b*c2b);
  size_t p0 = i0;
#define WRF16(R, va, vb) sth2(&((u16*)(ws + (size_t)(R)*NHS))[p0], va, vb);
  float nx = fsqrt(xsq+1e-15f);
  {
    float t = ftanh(nx);
    float f = fminf(t,PMX)*frcp(nx);
    float ny = fsqrt(f*f*xsq + 1e-15f);
    float g = fatanh(ny)*frcp(ny) * f;
    WRF16(0, g*xa, g*xb)
  }
  {
    float t = ftan(nx);
    float f = t*frcp(nx);
    float ny = fsqrt(f*f*xsq + 1e-15f);
    float g = fatan(ny)*frcp(ny) * f;
    WRF16(1, g*xa, g*xb)
  }
  WRF16(2, xa, xb)
  { float n=fsqrt(h1sq+1e-15f); float g=fatanh(n)*frcp(n); WRF16(3, g*h1a, g*h1b) }
  { float n=fsqrt(h2sq+1e-15f); float g=fatan(n)*frcp(n);  WRF16(4, g*h2a, g*h2b) }
  WRF16(5, h3a, h3b)
  { float n=fsqrt(c1sq+1e-15f); float g=fatanh(n)*frcp(n); WRF16(6, g*c1a, g*c1b) }
  { float n=fsqrt(c2sq+1e-15f); float g=fatan(n)*frcp(n);  WRF16(7, g*c2a, g*c2b) }
  WRF16(8, c3a, c3b)
#undef WRF16
}

// ---------------- MFMA f16 single-pass GEMM, TRANSPOSED output fragments (R9) ----------------
// acc[t] = mfma(W_frag, A_frag): lane nn holds the FULL output row (row0+nn), with
// 4 consecutive N-elems per (t,quad): n = t*16 + quad*4 + r. Row-scalar chains run ONCE
// per lane (was 4x), norms reduce in 2 shuffles (qred), stores are packed f16x4.
enum { P_ID=0, P_EXP_P, P_EXP_S, P_SIG, P_TANH, P_SIG_LOG_P, P_SIG_LOG_S,
       P_LOGSIG_P, P_LOGSIG_S, P_TANH_EXP_P, P_TANH_EXP_S };

struct JobM { const u16* A; const u16* W; const float* b; u16* out; int pitch; int post; };
struct JobTabM { JobM j[12]; };

__global__ __launch_bounds__(512) void k_gemmM(JobTabM tab){
  JobM jb = tab.j[blockIdx.y];
  __shared__ u16 Wlds[8*4*64*8];   // 32 KB, fragment-contiguous
  const int tid = threadIdx.x;
  const int lane = tid & 63;
  const int wave = tid >> 6;   // 0..7
  const int nn = lane & 15, quad = lane >> 4;
  const int row0 = blockIdx.x*128 + wave*16;
  // ---- prefetch A fragments FIRST (latency overlaps W staging) ----
  const u16* A = jb.A + (size_t)(row0+nn)*128 + quad*8;
  f16x8 a[4];
#pragma unroll
  for(int kk=0;kk<4;kk++) a[kk] = *(const f16x8*)(A + kk*32);
  // ---- stage W into LDS in fragment order ----
  for(int c = tid; c < 2048; c += 512){
    int lane_ = c & 63;
    int kk    = (c>>6)&3;
    int t     = (c>>8)&7;
    const u16* src = jb.W + (size_t)(t*16 + (lane_&15))*128 + (lane_>>4)*8 + kk*32;
    *(uint4*)&Wlds[(size_t)c*8] = *(const uint4*)src;
  }
  // bias: per-lane f32x4 per tile (n = t*16 + quad*4 + r)
  f32x4 bias4[8];
#pragma unroll
  for(int t=0;t<8;t++) bias4[t] = *(const f32x4*)&jb.b[t*16 + quad*4];
  __syncthreads();
  f32x4 acc[8];
#pragma unroll
  for(int t=0;t<8;t++) acc[t] = (f32x4){0.f,0.f,0.f,0.f};
#pragma unroll
  for(int kk=0;kk<4;kk++){
#pragma unroll
    for(int t=0;t<8;t++){
      f16x8 wh = *(const f16x8*)&Wlds[((t*4 + kk)*64 + lane)*8];
      acc[t] = __builtin_amdgcn_mfma_f32_16x16x32_f16(wh, a[kk], acc[t], 0,0,0);  // SWAPPED
    }
  }
  float v[32];
#pragma unroll
  for(int t=0;t<8;t++){
#pragma unroll
    for(int r=0;r<4;r++) v[t*4+r] = acc[t][r] + bias4[t][r];
  }
  switch(jb.post){
    case P_ID: break;
    case P_SIG:
      for(int i=0;i<32;i++) v[i]=sigm(v[i]);
      break;
    case P_TANH:
      for(int i=0;i<32;i++) v[i]=ftanh(v[i]);
      break;
    default: {
      float s2 = 0.f;
#pragma unroll
      for(int i=0;i<32;i++) s2 += v[i]*v[i];
      float nraw = qred(s2);
      switch(jb.post){
        case P_EXP_P: {
          float n=fsqrt(nraw+1e-15f); float tt=ftanh(n); float f=fminf(tt,PMX)*frcp(n);
          for(int i=0;i<32;i++) v[i]*=f;
        } break;
        case P_EXP_S: {
          float n=fsqrt(nraw+1e-15f); float f=ftan(n)*frcp(n);
          for(int i=0;i<32;i++) v[i]*=f;
        } break;
        case P_SIG_LOG_P: {
          float n=fsqrt(nraw+1e-15f); float tt=ftanh(n); float f=fminf(tt,PMX)*frcp(n);
          float z[32]; float zs=0.f;
          for(int i=0;i<32;i++){ z[i]=sigm(f*v[i]); zs+=z[i]*z[i]; }
          float zr=qred(zs);
          float zn=fsqrt(zr+1e-15f);
          float g=fatanh(zn)*frcp(zn);
          for(int i=0;i<32;i++) v[i]=g*z[i];
        } break;
        case P_SIG_LOG_S: {
          float n=fsqrt(nraw+1e-15f); float f=ftan(n)*frcp(n);
          float z[32]; float zs=0.f;
          for(int i=0;i<32;i++){ z[i]=sigm(f*v[i]); zs+=z[i]*z[i]; }
          float zr=qred(zs);
          float zn=fsqrt(zr+1e-15f);
          float g=fatan(zn)*frcp(zn);
          for(int i=0;i<32;i++) v[i]=g*z[i];
        } break;
        case P_LOGSIG_P: {
          float n=fsqrt(nraw+1e-15f); float tt=ftanh(n); float f=fminf(tt,PMX)*frcp(n);
          float ny=fsqrt(f*f*nraw+1e-15f);
          float g=fatanh(ny)*frcp(ny)*f;
          for(int i=0;i<32;i++) v[i]=sigm(g*v[i]);
        } break;
        case P_LOGSIG_S: {
          float n=fsqrt(nraw+1e-15f); float f=ftan(n)*frcp(n);
          float ny=fsqrt(f*f*nraw+1e-15f);
          float g=fatan(ny)*frcp(ny)*f;
          for(int i=0;i<32;i++) v[i]=sigm(g*v[i]);
        } break;
        case P_TANH_EXP_P: {
          float n=fsqrt(nraw+1e-15f); float tt=ftanh(n); float f=fminf(tt,PMX)*frcp(n);
          float ny=fsqrt(f*f*nraw+1e-15f);
          float g=fatanh(ny)*frcp(ny)*f;
          float T[32]; float Ts=0.f;
          for(int i=0;i<32;i++){ T[i]=ftanh(g*v[i]); Ts+=T[i]*T[i]; }
          float Tr=qred(Ts);
          float Tn=fsqrt(Tr+1e-15f);
          float t2=ftanh(Tn); float f2=fminf(t2,PMX)*frcp(Tn);
          for(int i=0;i<32;i++) v[i]=f2*T[i];
        } break;
        case P_TANH_EXP_S: {
          float n=fsqrt(nraw+1e-15f); float f=ftan(n)*frcp(n);
          float ny=fsqrt(f*f*nraw+1e-15f);
          float g=fatan(ny)*frcp(ny)*f;
          float T[32]; float Ts=0.f;
          for(int i=0;i<32;i++){ T[i]=ftanh(g*v[i]); Ts+=T[i]*T[i]; }
          float Tr=qred(Ts);
          float Tn=fsqrt(Tr+1e-15f);
          float f2=ftan(Tn)*frcp(Tn);
          for(int i=0;i<32;i++) v[i]=f2*T[i];
        } break;
      }
    } break;
  }
  // packed f16x4 stores: row = row0+nn, cols t*16 + quad*4 .. +3
  u16* obase = jb.out + (size_t)(row0 + nn)*jb.pitch + quad*4;
#pragma unroll
  for(int t=0;t<8;t++)
    *(f16x4*)&obase[t*16] = (f16x4){(f16)v[t*4],(f16)v[t*4+1],(f16)v[t*4+2],(f16)v[t*4+3]};
}

// ---------------- kernel 3: per-unique-node elementwise (phase B) ----------------
__global__ __launch_bounds__(256) void k_phaseB(
  const float* __restrict__ h1,const float* __restrict__ h2,const float* __restrict__ h3,
  const float* __restrict__ c1,const float* __restrict__ c2,const float* __restrict__ c3,
  const float* __restrict__ del_t, const float* __restrict__ dsc,
  float* __restrict__ ws)
{
  const u16* S1 = (const u16*)(ws+9*NHS);  const u16* S2 = (const u16*)(ws+10*NHS);
  const u16* S3 = (const u16*)(ws+11*NHS); const u16* F1 = (const u16*)(ws+12*NHS);
  const u16* F2 = (const u16*)(ws+13*NHS); const u16* F3 = (const u16*)(ws+14*NHS);
  const u16* Q1 = (const u16*)(ws+15*NHS); const u16* Q2 = (const u16*)(ws+16*NHS);
  const u16* Q3 = (const u16*)(ws+17*NHS);
  f16x2* PKP = (f16x2*)(ws+21*NHS);
  f16x2* PKS = (f16x2*)(ws+22*NHS);
  f16x2* PKE = (f16x2*)(ws+23*NHS);
  f16x4* PKV4= (f16x4*)(ws+24*NHS);
  f16x2* PKV2= (f16x2*)(ws+26*NHS);
  f32x4* SC4 = (f32x4*)(ws+SCOFF);

  int j = blockIdx.x*4 + (threadIdx.x>>6);
  int l = threadIdx.x&63;
  size_t i0 = (size_t)j*HD + 2*l;
  size_t pix = (size_t)j*64 + l;
#define LD2(p) (*(const f32x2*)&p[i0])
  f32x2 h1v=LD2(h1), h2v=LD2(h2), h3v=LD2(h3);
  f32x2 c1v=LD2(c1), c2v=LD2(c2), c3v=LD2(c3);
#undef LD2
  f32x2 s1v=ldh2(&S1[i0]), s2v=ldh2(&S2[i0]), s3v=ldh2(&S3[i0]);
  f32x2 f1v=ldh2(&F1[i0]), f2v=ldh2(&F2[i0]), f3v=ldh2(&F3[i0]);
  f32x2 q1v=ldh2(&Q1[i0]), q2v=ldh2(&Q2[i0]), q3v=ldh2(&Q3[i0]);
  float h1a=h1v[0],h1b=h1v[1], h2a=h2v[0],h2b=h2v[1], h3a=h3v[0],h3b=h3v[1];
  float c1a=c1v[0],c1b=c1v[1], c2a=c2v[0],c2b=c2v[1], c3a=c3v[0],c3b=c3v[1];
  float s1a=s1v[0],s1b=s1v[1], s2a=s2v[0],s2b=s2v[1], s3a=s3v[0],s3b=s3v[1];
  float f1a=f1v[0],f1b=f1v[1], f2a=f2v[0],f2b=f2v[1], f3a=f3v[0],f3b=f3v[1];
  float q1a=q1v[0],q1b=q1v[1], q2a=q2v[0],q2b=q2v[1], q3a=q3v[0],q3b=q3v[1];
  float g = fdiv(dsc[0], del_t[j]+1.0f);

  float h1sq = wred(h1a*h1a+h1b*h1b); float n1 = fsqrt(h1sq+1e-15f);
  float h2sq = wred(h2a*h2a+h2b*h2b); float n2 = fsqrt(h2sq+1e-15f);
  float h3sq = wred(h3a*h3a+h3b*h3b); float n3 = fsqrt(h3sq+1e-15f);
  float w1a=s1a*h1a, w1b=s1b*h1b;
  float w2a=s2a*h2a, w2b=s2b*h2b;
  float w3a=s3a*h3a, w3b=s3b*h3b;
  float w1sq = wred(w1a*w1a+w1b*w1b); float nw1 = fsqrt(w1sq+1e-15f);
  float w2sq = wred(w2a*w2a+w2b*w2b); float nw2 = fsqrt(w2sq+1e-15f);
  float w3sq = wred(w3a*w3a+w3b*w3b); float nw3 = fsqrt(w3sq+1e-15f);

  // ---- h_1p
  float t1 = ftanh(nw1*frcp(n1) * fatanh(n1));
  float fp1 = fminf(t1,PMX)*frcp(nw1); float np1 = fminf(t1,PMX);
  float nu2 = fatan(n2);
  float ne2 = fminf(ftanh(nu2),PMX);
  float t2 = ftanh(nw2*frcp(n2) * fatanh(ne2));
  float fp2 = fminf(t2,PMX)*frcp(nw2); float np2 = fminf(t2,PMX);
  float ne3 = fminf(ftanh(n3),PMX);
  float t3 = ftanh(nw3*frcp(n3) * fatanh(ne3));
  float fp3 = fminf(t3,PMX)*frcp(nw3); float np3 = fminf(t3,PMX);
  float y2pv;
  {
    float lamA = 2.0f*frcp(1.0f-np1*np1), lamB = 2.0f*frcp(1.0f-np2*np2), lamC = 2.0f*frcp(1.0f-np3*np3);
    float dn = frcp(fmaxf(fabsf(lamA+lamB+lamC-3.0f), EPSF));
    float va = (lamA*fp1*w1a + lamB*fp2*w2a + lamC*fp3*w3a)*dn;
    float vb = (lamA*fp1*w1b + lamB*fp2*w2b + lamC*fp3*w3b)*dn;
    float vsq = wred(va*va+vb*vb); float nv = fsqrt(vsq+1e-15f);
    float tt = ftanh(0.5f*fatanh(nv)); float ff = 3.0f*fminf(tt,PMX)*frcp(nv);
    PKP[pix] = (f16x2){(f16)(ff*va), (f16)(ff*vb)};
    y2pv = ff*ff*vsq;
  }
  // ---- h_1s
  float t2s, fs2, y2sv;
  {
    float nx1s = ftan(fatanh(n1));
    float t1s = ftanh(nw1*frcp(n1) * fatanh(nx1s));
    float fs1 = fminf(t1s,PMX)*frcp(nw1); float ns1 = fminf(t1s,PMX);
    t2s = ftan(nw2*frcp(n2) * fatan(n2));
    fs2 = t2s*frcp(nw2);
    float nx3s = ftan(n3);
    float t3s = ftan(nw3*frcp(n3) * fatan(nx3s));
    float fs3 = t3s*frcp(nw3);
    float lA = 2.0f*frcp(1.0f-ns1*ns1), lB = 2.0f*frcp(1.0f-t2s*t2s), lC = 2.0f*frcp(1.0f-t3s*t3s);
    float dns = frcp(fmaxf(fabsf(lA+lB+lC-3.0f), EPSF));
    float vsa = (lA*fs1*w1a + lB*fs2*w2a + lC*fs3*w3a)*dns;
    float vsb = (lA*fs1*w1b + lB*fs2*w2b + lC*fs3*w3b)*dns;
    float vssq = wred(vsa*vsa+vsb*vsb); float nvs = fsqrt(vssq+1e-15f);
    float tts = ftan(0.5f*fatan(nvs)); float ffs = 3.0f*tts*frcp(nvs);
    PKS[pix] = (f16x2){(f16)(ffs*vsa), (f16)(ffs*vsb)};
    y2sv = ffs*ffs*vssq;
  }
  // ---- h_1e
  {
    float ne1 = fsqrt(fp1*fp1*w1sq + 1e-15f);
    float ge1 = fatanh(ne1)*frcp(ne1);
    float n2s_ = fsqrt(fs2*fs2*w2sq + 1e-15f);
    float ge2 = fatan(n2s_)*frcp(n2s_);
    float h1ea = ge1*fp1*w1a + ge2*fs2*w2a + s3a*h3a;
    float h1eb = ge1*fp1*w1b + ge2*fs2*w2b + s3b*h3b;
    PKE[pix] = (f16x2){(f16)h1ea, (f16)h1eb};
  }
  float ng = fsqrt(g*g+1e-15f);
  // ---- Poincare cell
  float v1xa,v1xb,d1v;
  {
    float q1sq = wred(q1a*q1a+q1b*q1b);
    float c1rs = wred(c1a*c1a+c1b*c1b);
    float dq1 = wred(q1a*c1a+q1b*c1b);
    float xy = -dq1;
    float aa = 1.0f+2.0f*xy+c1rs, bb = 1.0f-q1sq;
    float dd = frcp(safeden(1.0f+2.0f*xy+q1sq*c1rs));
    float m1a = (aa*(-q1a)+bb*c1a)*dd, m1b = (aa*(-q1b)+bb*c1b)*dd;
    float m1sq = (aa*aa*q1sq + 2.0f*aa*bb*xy + bb*bb*c1rs)*dd*dd;
    float mdq = (-aa*q1sq + bb*dq1)*dd;
    { float nm = fsqrt(m1sq+1e-15f);
      if(nm>PMX){ float sc=PMX*frcp(nm); m1a*=sc; m1b*=sc; m1sq*=sc*sc; mdq*=sc; } }
    float nwg = fsqrt(g*g*q1sq+1e-15f);
    float tg = ftanh(nwg*frcp(ng) * fatanh(ng));
    float fX = fminf(tg,PMX)*frcp(nwg) * g;
    float X2sq = fX*fX*q1sq;
    float xy2 = fX*mdq;
    float a2 = 1.0f+2.0f*xy2+X2sq, b2 = 1.0f-m1sq;
    float d2d = frcp(safeden(1.0f+2.0f*xy2+m1sq*X2sq));
    float ka = (a2*m1a + b2*fX*q1a)*d2d, kb = (a2*m1b + b2*fX*q1b)*d2d;
    float ksq = (a2*a2*m1sq + 2.0f*a2*b2*xy2 + b2*b2*X2sq)*d2d*d2d;
    { float nk0 = fsqrt(ksq+1e-15f);
      if(nk0>PMX){ float sc=PMX*frcp(nk0); ka*=sc; kb*=sc; ksq*=sc*sc; } }
    float nk = fsqrt(ksq+1e-15f);
    float wfa = f1a*ka, wfb = f1b*kb;
    float wfsq = wred(wfa*wfa+wfb*wfb); float nwf = fsqrt(wfsq+1e-15f);
    float tu = ftanh(nwf*frcp(nk) * fatanh(nk));
    float fu = fminf(tu,PMX)*frcp(nwf);
    float u1sq = fu*fu*wfsq;
    float lam = 2.0f*frcp(1.0f-u1sq);
    v1xa=lam*fu*wfa; v1xb=lam*fu*wfb;
    d1v=lam-1.0f;
  }
  // ---- Sphere cell
  float v2xa,v2xb,d2v;
  {
    float q2sq = wred(q2a*q2a+q2b*q2b);
    float c2rs = wred(c2a*c2a+c2b*c2b);
    float dq2 = wred(q2a*c2a+q2b*c2b);
    float xy = -dq2;
    float aa = 1.0f-2.0f*xy-c2rs, bb = 1.0f+q2sq;
    float dd = frcp(safeden(1.0f-2.0f*xy+q2sq*c2rs));
    float ma = (aa*(-q2a)+bb*c2a)*dd, mb = (aa*(-q2b)+bb*c2b)*dd;
    float msq = (aa*aa*q2sq + 2.0f*aa*bb*xy + bb*bb*c2rs)*dd*dd;
    float mdq = (-aa*q2sq + bb*dq2)*dd;
    float nwg = fsqrt(g*g*q2sq+1e-15f);
    float tg = ftan(nwg*frcp(ng) * fatan(ng));
    float fX = tg*frcp(nwg) * g;
    float X2sq = fX*fX*q2sq;
    float xy2 = fX*mdq;
    float a2 = 1.0f-2.0f*xy2-X2sq, b2 = 1.0f+msq;
    float d2d = frcp(safeden(1.0f-2.0f*xy2+msq*X2sq));
    float ka = (a2*ma + b2*fX*q2a)*d2d, kb = (a2*mb + b2*fX*q2b)*d2d;
    float ksq = (a2*a2*msq + 2.0f*a2*b2*xy2 + b2*b2*X2sq)*d2d*d2d;
    float nk = fsqrt(ksq+1e-15f);
    float wfa = f2a*ka, wfb = f2b*kb;
    float wfsq = wred(wfa*wfa+wfb*wfb); float nwf = fsqrt(wfsq+1e-15f);
    float tu = ftan(nwf*frcp(nk) * fatan(nk));
    float fu = tu*frcp(nwf);
    float u2sq = fu*fu*wfsq;
    float lam = 2.0f*frcp(1.0f+u2sq);
    v2xa=lam*fu*wfa; v2xb=lam*fu*wfb;
    d2v=lam-1.0f;
  }
  // ---- Euclid cell
  float v3xa,v3xb;
  {
    float kea = c3a + q3a*(g-1.0f), keb = c3b + q3b*(g-1.0f);
    v3xa=f3a*kea; v3xb=f3b*keb;
  }
  PKV4[pix] = (f16x4){(f16)v1xa,(f16)v1xb,(f16)v2xa,(f16)v2xb};
  PKV2[pix] = (f16x2){(f16)v3xa,(f16)v3xb};
  if(l==0) SC4[j] = (f32x4){y2pv,y2sv,d1v,d2v};
}

// ---------------- kernel 4: attention + K-reductions (4 specialized waves per node) ----------------
__global__ __launch_bounds__(256) void k_attn(
  const int* __restrict__ nbr, float* __restrict__ ws)
{
  const f16x2* PKP = (const f16x2*)(ws+21*NHS);
  const f16x2* PKS = (const f16x2*)(ws+22*NHS);
  const f16x2* PKE = (const f16x2*)(ws+23*NHS);
  const f16x4* PKV4= (const f16x4*)(ws+24*NHS);
  const f16x2* PKV2= (const f16x2*)(ws+26*NHS);
  const float* SCf = ws+SCOFF;
  u16* LP = (u16*)(ws+9*NHS);
  u16* LS = (u16*)(ws+10*NHS);
  u16* LE = (u16*)(ws+11*NHS);
  u16* C1o = (u16*)(ws+12*NHS); u16* C2o = (u16*)(ws+13*NHS); u16* C3o = (u16*)(ws+14*NHS);
  float* c1n2 = ws+SCOFF+32768; float* c2n2 = ws+SCOFF+40960;

  int n = blockIdx.x;
  int wv = threadIdx.x>>6;
  int l = threadIdx.x&63;
  size_t i0 = (size_t)n*HD + 2*l;
  int4 jA = ((const int4*)nbr)[n*2+0];
  int4 jB = ((const int4*)nbr)[n*2+1];
  int js[8] = {jA.x,jA.y,jA.z,jA.w,jB.x,jB.y,jB.z,jB.w};

  if(wv==0){
    // ---- Poincare attention ----
    const u16* XP = (const u16*)(ws+18*NHS);
    f32x2 xv = ldh2(&XP[i0]);
    float XPa=xv[0], XPb=xv[1];
    float x2p = wred(XPa*XPa+XPb*XPb);
    float Ha[8],Hb[8],y2k[8];
#pragma unroll
    for(int k=0;k<8;k++){
      int j = js[k];
      f16x2 h = PKP[(size_t)j*64+l];
      Ha[k]=(float)h[0]; Hb[k]=(float)h[1];
      y2k[k]=SCf[(size_t)j*4+0];
    }
    float sc[8];
#pragma unroll
    for(int k=0;k<8;k++){
      float dp = wred(XPa*Ha[k]+XPb*Hb[k]);
      float xy=-dp, y2=y2k[k];
      float aa=1.0f+2.0f*xy+y2, bb=1.0f-x2p;
      float dd=frcp(safeden(1.0f+2.0f*xy+x2p*y2));
      float nsq=(aa*aa*x2p+2.0f*aa*bb*xy+bb*bb*y2)*dd*dd;
      float nn=fminf(fsqrt(nsq+1e-15f),PMX);
      sc[k] = -2.0f*fatanh(nn);
    }
    float mx=sc[0];
#pragma unroll
    for(int k=1;k<8;k++) mx=fmaxf(mx,sc[k]);
    float a[8]; float s=0;
#pragma unroll
    for(int k=0;k<8;k++){ a[k]=fexp(sc[k]-mx); s+=a[k]; }
    float inv=frcp(s);
    float na=0,nb=0,de=0;
#pragma unroll
    for(int k=0;k<8;k++){
      float lam = 2.0f*frcp(1.0f-y2k[k]); float w=a[k]*inv;
      na+=w*lam*Ha[k]; nb+=w*lam*Hb[k]; de+=w*(lam-1.0f);
    }
    de = frcp(fmaxf(fabsf(de),EPSF));
    na*=de; nb*=de;
    float vsq=wred(na*na+nb*nb); float nv=fsqrt(vsq+1e-15f);
    float tt=ftanh(0.5f*fatanh(nv)); float f=fminf(tt,PMX)*frcp(nv);
    float ha=f*na, hb=f*nb;
    float hn=fsqrt(f*f*vsq+1e-15f);
    float gl=fatanh(hn)*frcp(hn);
    sth2(&LP[i0], gl*ha, gl*hb);
  } else if(wv==1){
    // ---- Sphere attention ----
    const u16* XS = (const u16*)(ws+19*NHS);
    f32x2 xv = ldh2(&XS[i0]);
    float XSa=xv[0], XSb=xv[1];
    float x2s = wred(XSa*XSa+XSb*XSb);
    float Ha[8],Hb[8],y2k[8];
#pragma unroll
    for(int k=0;k<8;k++){
      int j = js[k];
      f16x2 h = PKS[(size_t)j*64+l];
      Ha[k]=(float)h[0]; Hb[k]=(float)h[1];
      y2k[k]=SCf[(size_t)j*4+1];
    }
    float sc[8];
#pragma unroll
    for(int k=0;k<8;k++){
      float dsv = wred(XSa*Ha[k]+XSb*Hb[k]);
      float xy=-dsv, y2=y2k[k];
      float aa=1.0f-2.0f*xy-y2, bb=1.0f+x2s;
      float dd=frcp(safeden(1.0f-2.0f*xy+x2s*y2));
      float nsq=(aa*aa*x2s+2.0f*aa*bb*xy+bb*bb*y2)*dd*dd;
      float nn=fsqrt(nsq+1e-15f);
      sc[k] = -2.0f*fatan(nn);
    }
    float mx=sc[0];
#pragma unroll
    for(int k=1;k<8;k++) mx=fmaxf(mx,sc[k]);
    float a[8]; float s=0;
#pragma unroll
    for(int k=0;k<8;k++){ a[k]=fexp(sc[k]-mx); s+=a[k]; }
    float inv=frcp(s);
    float na=0,nb=0,de=0;
#pragma unroll
    for(int k=0;k<8;k++){
      float lam = 2.0f*frcp(1.0f+y2k[k]); float w=a[k]*inv;
      na+=w*lam*Ha[k]; nb+=w*lam*Hb[k]; de+=w*(lam-1.0f);
    }
    de = frcp(fmaxf(fabsf(de),EPSF));
    na*=de; nb*=de;
    float vsq=wred(na*na+nb*nb); float nv=fsqrt(vsq+1e-15f);
    float tt=ftan(0.5f*fatan(nv)); float f=tt*frcp(nv);
    float ha=f*na, hb=f*nb;
    float hn=fsqrt(f*f*vsq+1e-15f);
    float gl=fatan(hn)*frcp(hn);
    sth2(&LS[i0], gl*ha, gl*hb);
  } else if(wv==2){
    // ---- Euclid attention ----
    const u16* XE = (const u16*)(ws+20*NHS);
    const float rs = 0.08838834764831845f;
    f32x2 xv = ldh2(&XE[i0]);
    float XEa=xv[0], XEb=xv[1];
    float Ha[8],Hb[8];
#pragma unroll
    for(int k=0;k<8;k++){
      int j = js[k];
      f16x2 h = PKE[(size_t)j*64+l];
      Ha[k]=(float)h[0]; Hb[k]=(float)h[1];
    }
    float sc[8];
#pragma unroll
    for(int k=0;k<8;k++) sc[k] = wred(XEa*Ha[k]+XEb*Hb[k])*rs;
    float mx=sc[0];
#pragma unroll
    for(int k=1;k<8;k++) mx=fmaxf(mx,sc[k]);
    float a[8]; float s=0;
#pragma unroll
    for(int k=0;k<8;k++){ a[k]=fexp(sc[k]-mx); s+=a[k]; }
    float inv=frcp(s);
    float ha=0,hb=0;
#pragma unroll
    for(int k=0;k<8;k++){ float w=a[k]*inv; ha+=w*Ha[k]; hb+=w*Hb[k]; }
    sth2(&LE[i0], ha, hb);
  } else {
    // ---- cell-path V sums + outputs ----
    float v1a=0,v1b=0,v2a=0,v2b=0,v3a=0,v3b=0,ds1=0,ds2=0;
#pragma unroll
    for(int k=0;k<8;k++){
      int j = js[k];
      f16x4 v4 = PKV4[(size_t)j*64+l];
      f16x2 v2 = PKV2[(size_t)j*64+l];
      v1a+=(float)v4[0]; v1b+=(float)v4[1]; v2a+=(float)v4[2]; v2b+=(float)v4[3];
      v3a+=(float)v2[0]; v3b+=(float)v2[1];
      ds1+=SCf[(size_t)j*4+2]; ds2+=SCf[(size_t)j*4+3];
    }
    { // c_1
      float de=frcp(fmaxf(fabsf(ds1),EPSF));
      float na=v1a*de, nb=v1b*de;
      float vsq=wred(na*na+nb*nb); float nv=fsqrt(vsq+1e-15f);
      float tt=ftanh(0.5f*fatanh(nv)); float f=fminf(tt,PMX)*frcp(nv);
      sth2(&C1o[i0], f*na, f*nb);
      if(l==0) c1n2[n]=f*f*vsq;
    }
    { // c_2
      float de=frcp(fmaxf(fabsf(ds2),EPSF));
      float na=v2a*de, nb=v2b*de;
      float vsq=wred(na*na+nb*nb); float nv=fsqrt(vsq+1e-15f);
      float tt=ftan(0.5f*fatan(nv)); float f=tt*frcp(nv);
      sth2(&C2o[i0], f*na, f*nb);
      if(l==0) c2n2[n]=f*f*vsq;
    }
    sth2(&C3o[i0], v3a, v3b);
  }
}

// ---------------- kernel 6: final epilogue ----------------
__global__ __launch_bounds__(256) void k_final(
  const float* __restrict__ iou1, const float* __restrict__ iou2,
  const float* __restrict__ iou3, float* __restrict__ ws,
  float* __restrict__ out)
{
  const u16* YP = (const u16*)ws;
  const u16* YS = (const u16*)(ws+3*NHS);
  const u16* YE = (const u16*)(ws+6*NHS);
  const u16* C1v = (const u16*)(ws+12*NHS);
  const u16* C2v = (const u16*)(ws+13*NHS);
  const u16* C3v = (const u16*)(ws+14*NHS);
  const float* c1n2 = ws+SCOFF+32768; const float* c2n2 = ws+SCOFF+40960;
  int n = blockIdx.x*4 + (threadIdx.x>>6);
  int l = threadIdx.x&63;
  size_t b384 = (size_t)n*384 + 2*l;
  size_t b128 = (size_t)n*HD + 2*l;
  // ================= Poincare =================
  {
    float Y[6], I[6];
#pragma unroll
    for(int p=0;p<3;p++){
      f32x2 yv = ldh2(&YP[b384 + 128*p]);
      f32x2 iv = *(const f32x2*)&iou1[b384 + 128*p];
      Y[2*p]=yv[0]; Y[2*p+1]=yv[1]; I[2*p]=iv[0]; I[2*p+1]=iv[1];
    }
    float sy=0,si=0,sx=0;
#pragma unroll
    for(int r=0;r<6;r++){ sy+=Y[r]*Y[r]; si+=I[r]*I[r]; sx+=I[r]*Y[r]; }
    sy=wred(sy); si=wred(si); sx=wred(sx);
    float nY=fsqrt(sy+1e-15f);
    float te=ftanh(nY); float fE=fminf(te,PMX)*frcp(nY);
    float y2=fE*fE*sy, x2=si, xy=fE*sx;
    float aa=1.0f+2.0f*xy+y2, bb=1.0f-x2;
    float dd=frcp(safeden(1.0f+2.0f*xy+x2*y2));
    float nio[6];
#pragma unroll
    for(int r=0;r<6;r++) nio[r]=(aa*I[r]+bb*fE*Y[r])*dd;
    float nsq=(aa*aa*x2+2.0f*aa*bb*xy+bb*bb*y2)*dd*dd;
    { float nn=fsqrt(nsq+1e-15f);
      if(nn>PMX){ float sc=PMX*frcp(nn); for(int r=0;r<6;r++) nio[r]*=sc; } }
    float ci=wred(nio[0]*nio[0]+nio[1]*nio[1]); float ni=fsqrt(ci+1e-15f); float gi=fatanh(ni)*frcp(ni);
    float ip0=sigm(gi*nio[0]), ip1=sigm(gi*nio[1]);
    float co=wred(nio[2]*nio[2]+nio[3]*nio[3]); float no=fsqrt(co+1e-15f); float go=fatanh(no)*frcp(no);
    float op0=sigm(go*nio[2]), op1=sigm(go*nio[3]);
    float cu=wred(nio[4]*nio[4]+nio[5]*nio[5]); float nu=fsqrt(cu+1e-15f); float gu=fatanh(nu)*frcp(nu);
    float up0=ftanh(gu*nio[4]), up1=ftanh(gu*nio[5]);
    float usq=wred(up0*up0+up1*up1); float nx=fsqrt(usq+1e-15f);
    float wv0=ip0*up0, wv1=ip1*up1;
    float wsq=wred(wv0*wv0+wv1*wv1); float nwx=fsqrt(wsq+1e-15f);
    float tP=ftanh(nwx*frcp(nx)*fatanh(nx)); float fP=fminf(tP,PMX)*frcp(nwx);
    float P0=fP*wv0, P1=fP*wv1; float p2=fP*fP*wsq;
    f32x2 cv = ldh2(&C1v[b128]);
    float ca=cv[0], cb=cv[1];
    float y2c=c1n2[n];
    float xyc=wred(P0*ca+P1*cb);
    float a3=1.0f+2.0f*xyc+y2c, b3=1.0f-p2;
    float d3=frcp(safeden(1.0f+2.0f*xyc+p2*y2c));
    float nc0=(a3*P0+b3*ca)*d3, nc1_=(a3*P1+b3*cb)*d3;
    float ncsq=(a3*a3*p2+2.0f*a3*b3*xyc+b3*b3*y2c)*d3*d3;
    { float nn=fsqrt(ncsq+1e-15f);
      if(nn>PMX){ float sc=PMX*frcp(nn); nc0*=sc; nc1_*=sc; ncsq*=sc*sc; } }
    float nl=fsqrt(ncsq+1e-15f);
    float gL=fatanh(nl)*frcp(nl);
    float T0=ftanh(gL*nc0), T1=ftanh(gL*nc1_);
    float tsq=wred(T0*T0+T1*T1); float nT=fsqrt(tsq+1e-15f);
    float wo0=op0*T0, wo1=op1*T1;
    float osq=wred(wo0*wo0+wo1*wo1); float nwo=fsqrt(osq+1e-15f);
    float tH=ftanh(nwo*frcp(nT)*fatanh(nT)); float fH=fminf(tH,PMX)*frcp(nwo);
    *(f32x2*)&out[0*NHS + b128] = (f32x2){fH*wo0, fH*wo1};
    *(f32x2*)&out[1*NHS + b128] = (f32x2){nc0, nc1_};
  }
  // ================= Sphere =================
  {
    float Y[6], I[6];
#pragma unroll
    for(int p=0;p<3;p++){
      f32x2 yv = ldh2(&YS[b384 + 128*p]);
      f32x2 iv = *(const f32x2*)&iou2[b384 + 128*p];
      Y[2*p]=yv[0]; Y[2*p+1]=yv[1]; I[2*p]=iv[0]; I[2*p+1]=iv[1];
    }
    float sy=0,si=0,sx=0;
#pragma unroll
    for(int r=0;r<6;r++){ sy+=Y[r]*Y[r]; si+=I[r]*I[r]; sx+=I[r]*Y[r]; }
    sy=wred(sy); si=wred(si); sx=wred(sx);
    float nY=fsqrt(sy+1e-15f);
    float te=ftan(nY); float fE=te*frcp(nY);
    float y2=fE*fE*sy, x2=si, xy=fE*sx;
    float aa=1.0f-2.0f*xy-y2, bb=1.0f+x2;
    float dd=frcp(safeden(1.0f-2.0f*xy+x2*y2));
    float nio[6];
#pragma unroll
    for(int r=0;r<6;r++) nio[r]=(aa*I[r]+bb*fE*Y[r])*dd;
    float ci=wred(nio[0]*nio[0]+nio[1]*nio[1]); float ni=fsqrt(ci+1e-15f); float gi=fatan(ni)*frcp(ni);
    float ip0=sigm(gi*nio[0]), ip1=sigm(gi*nio[1]);
    float co=wred(nio[2]*nio[2]+nio[3]*nio[3]); float no=fsqrt(co+1e-15f); float go=fatan(no)*frcp(no);
    float op0=sigm(go*nio[2]), op1=sigm(go*nio[3]);
    float cu=wred(nio[4]*nio[4]+nio[5]*nio[5]); float nu=fsqrt(cu+1e-15f); float gu=fatan(nu)*frcp(nu);
    float up0=ftanh(gu*nio[4]), up1=ftanh(gu*nio[5]);
    float usq=wred(up0*up0+up1*up1); float nx=fsqrt(usq+1e-15f);
    float wv0=ip0*up0, wv1=ip1*up1;
    float wsq=wred(wv0*wv0+wv1*wv1); float nwx=fsqrt(wsq+1e-15f);
    float tP=ftan(nwx*frcp(nx)*fatan(nx)); float fP=tP*frcp(nwx);
    float P0=fP*wv0, P1=fP*wv1; float p2=fP*fP*wsq;
    f32x2 cv = ldh2(&C2v[b128]);
    float ca=cv[0], cb=cv[1];
    float y2c=c2n2[n];
    float xyc=wred(P0*ca+P1*cb);
    float a3=1.0f-2.0f*xyc-y2c, b3=1.0f+p2;
    float d3=frcp(safeden(1.0f-2.0f*xyc+p2*y2c));
    float nc0=(a3*P0+b3*ca)*d3, nc1_=(a3*P1+b3*cb)*d3;
    float ncsq=(a3*a3*p2+2.0f*a3*b3*xyc+b3*b3*y2c)*d3*d3;
    float nl=fsqrt(ncsq+1e-15f);
    float gL=fatan(nl)*frcp(nl);
    float T0=ftanh(gL*nc0), T1=ftanh(gL*nc1_);
    float tsq=wred(T0*T0+T1*T1); float nT=fsqrt(tsq+1e-15f);
    float wo0=op0*T0, wo1=op1*T1;
    float osq=wred(wo0*wo0+wo1*wo1); float nwo=fsqrt(osq+1e-15f);
    float tH=ftan(nwo*frcp(nT)*fatan(nT)); float fH=tH*frcp(nwo);
    *(f32x2*)&out[2*NHS + b128] = (f32x2){fH*wo0, fH*wo1};
    *(f32x2*)&out[3*NHS + b128] = (f32x2){nc0, nc1_};
  }
  // ================= Euclid =================
  {
    float Y[6], I[6];
#pragma unroll
    for(int p=0;p<3;p++){
      f32x2 yv = ldh2(&YE[b384 + 128*p]);
      f32x2 iv = *(const f32x2*)&iou3[b384 + 128*p];
      Y[2*p]=yv[0]; Y[2*p+1]=yv[1]; I[2*p]=iv[0]; I[2*p+1]=iv[1];
    }
    float n0=I[0]+Y[0], n1=I[1]+Y[1];
    float n2=I[2]+Y[2], n3=I[3]+Y[3];
    float n4=I[4]+Y[4], n5=I[5]+Y[5];
    float ie0=sigm(n0), ie1=sigm(n1);
    float oe0=sigm(n2), oe1=sigm(n3);
    float ue0=ftanh(n4), ue1=ftanh(n5);
    f32x2 cv = ldh2(&C3v[b128]);
    float ca=cv[0], cb=cv[1];
    float nc0=ie0*ue0+ca, nc1_=ie1*ue1+cb;
    *(f32x2*)&out[4*NHS + b128] = (f32x2){oe0*ftanh(nc0), oe1*ftanh(nc1_)};
    *(f32x2*)&out[5*NHS + b128] = (f32x2){nc0, nc1_};
  }
}

extern "C" void kernel_launch(void* const* d_in, const int* in_sizes, int n_in,
                              void* d_out, int out_size, void* d_ws, size_t ws_size,
                              hipStream_t stream)
{
  const float* x     = (const float*)d_in[0];
  const float* h1    = (const float*)d_in[1];
  const float* c1    = (const float*)d_in[2];
  const float* h2    = (const float*)d_in[3];
  const float* c2    = (const float*)d_in[4];
  const float* h3    = (const float*)d_in[5];
  const float* c3    = (const float*)d_in[6];
  const float* del_t = (const float*)d_in[7];
  const float* iou1  = (const float*)d_in[8];
  const float* iou2  = (const float*)d_in[9];
  const float* iou3  = (const float*)d_in[10];
  const float* Wq_w  = (const float*)d_in[11];
  const float* Wq_b  = (const float*)d_in[12];
  const float* Wc_w  = (const float*)d_in[13];
  const float* Wc_b  = (const float*)d_in[14];
  const float* Uf_w  = (const float*)d_in[15];
  const float* Uf_b  = (const float*)d_in[16];
  const float* Up_w  = (const float*)d_in[17];
  const float* Up_b  = (const float*)d_in[18];
  const float* Uiou_w= (const float*)d_in[19];
  const float* Uiou_b= (const float*)d_in[20];
  const float* dsc   = (const float*)d_in[21];
  const int*   nbr   = (const int*)d_in[22];
  float* out = (float*)d_out;
  float* ws  = (float*)d_ws;

  // fused weight f16-convert + row pre-transforms
  k_pre<<<2160,256,0,stream>>>(x,h1,h2,c1,c2,h3,c3,Wq_w,Wc_w,Uf_w,Up_w,Uiou_w,ws);

  u16* WH = (u16*)(ws + WOFF);
  const u16* Wqh = WH;
  const u16* Wch = WH + 16384;
  const u16* Ufh = WH + 32768;
  const u16* Uph = WH + 49152;
  const u16* UIh = WH + 65536;
#define APLANE(R) ((const u16*)(ws + (size_t)(R)*NHS))

  JobTabM A{};
  A.j[0]  = { APLANE(0), Wqh, Wq_b, (u16*)(ws+18*NHS), 128, P_EXP_P };      // XP
  A.j[1]  = { APLANE(1), Wqh, Wq_b, (u16*)(ws+19*NHS), 128, P_EXP_S };      // XS
  A.j[2]  = { APLANE(2), Wqh, Wq_b, (u16*)(ws+20*NHS), 128, P_ID };         // XE
  A.j[3]  = { APLANE(3), Uph, Up_b, (u16*)(ws+9*NHS),  128, P_SIG_LOG_P };  // S1
  A.j[4]  = { APLANE(4), Uph, Up_b, (u16*)(ws+10*NHS), 128, P_SIG_LOG_S };  // S2
  A.j[5]  = { APLANE(5), Uph, Up_b, (u16*)(ws+11*NHS), 128, P_SIG };        // S3
  A.j[6]  = { APLANE(3), Ufh, Uf_b, (u16*)(ws+12*NHS), 128, P_LOGSIG_P };   // F1
  A.j[7]  = { APLANE(4), Ufh, Uf_b, (u16*)(ws+13*NHS), 128, P_LOGSIG_S };   // F2
  A.j[8]  = { APLANE(5), Ufh, Uf_b, (u16*)(ws+14*NHS), 128, P_SIG };        // F3
  A.j[9]  = { APLANE(6), Wch, Wc_b, (u16*)(ws+15*NHS), 128, P_TANH_EXP_P }; // CS1
  A.j[10] = { APLANE(7), Wch, Wc_b, (u16*)(ws+16*NHS), 128, P_TANH_EXP_S }; // CS2
  A.j[11] = { APLANE(8), Wch, Wc_b, (u16*)(ws+17*NHS), 128, P_TANH };       // CS3
  k_gemmM<<<dim3(NNODE/128,12),512,0,stream>>>(A);

  k_phaseB<<<2048,256,0,stream>>>(h1,h2,h3,c1,c2,c3,del_t,dsc,ws);
  k_attn<<<8192,256,0,stream>>>(nbr,ws);

  JobTabM B{};
  for(int ct=0; ct<3; ct++){
    B.j[0*3+ct] = { APLANE(9),  UIh + ct*16384, Uiou_b + ct*128, (u16*)(ws+0*NHS) + ct*128, 384, P_ID };
    B.j[1*3+ct] = { APLANE(10), UIh + ct*16384, Uiou_b + ct*128, (u16*)(ws+3*NHS) + ct*128, 384, P_ID };
    B.j[2*3+ct] = { APLANE(11), UIh + ct*16384, Uiou_b + ct*128, (u16*)(ws+6*NHS) + ct*128, 384, P_ID };
  }
  k_gemmM<<<dim3(NNODE/128,9),512,0,stream>>>(B);

  k_final<<<2048,256,0,stream>>>(iou1,iou2,iou3,ws,out);
}

// Round 10
// 225.659 us; speedup vs baseline: 1.0328x; 1.0328x over previous
//
#include <hip/hip_runtime.h>
#include <math.h>

#define HD 128
#define NNODE 8192
#define KNBR 8
#define NHS ((size_t)NNODE*(size_t)HD)

#define EPSF 1e-6f
#define PMX 0.9999f
#define ATHC (1.0f-1e-5f)
#define TANC 1.47079f

typedef unsigned short u16;
typedef unsigned int u32;
typedef _Float16 f16;
typedef __attribute__((ext_vector_type(4))) float f32x4;
typedef __attribute__((ext_vector_type(2))) float f32x2;
typedef __attribute__((ext_vector_type(2))) _Float16 f16x2;
typedef __attribute__((ext_vector_type(4))) _Float16 f16x4;
typedef __attribute__((ext_vector_type(8))) _Float16 f16x8;

// ---------- fast hardware math ----------
static __device__ __forceinline__ float frcp(float x){ return __builtin_amdgcn_rcpf(x); }
static __device__ __forceinline__ float fdiv(float a,float b){ return a*__builtin_amdgcn_rcpf(b); }
static __device__ __forceinline__ float fsqrt(float x){ return __builtin_amdgcn_sqrtf(x); }
static __device__ __forceinline__ float fexp(float x){ return __builtin_amdgcn_exp2f(x*1.4426950408889634f); }
static __device__ __forceinline__ float flog(float x){ return __builtin_amdgcn_logf(x)*0.6931471805599453f; }
static __device__ __forceinline__ float ftanh(float x){
  float ax = fabsf(x);
  float e = fexp(-2.0f*ax);
  float t = (1.0f-e)*frcp(1.0f+e);
  return copysignf(t,x);
}
static __device__ __forceinline__ float fatanh(float x){
  x = fminf(fmaxf(x,-ATHC),ATHC);
  return 0.5f*flog((1.0f+x)*frcp(1.0f-x));
}
static __device__ __forceinline__ float fatan(float x){
  float ax = fabsf(x);
  bool inv = ax > 1.0f;
  float t = inv ? frcp(ax) : ax;
  float t2 = t*t;
  float p = -0.0117212f;
  p = p*t2 + 0.05265332f;
  p = p*t2 - 0.11643287f;
  p = p*t2 + 0.19354346f;
  p = p*t2 - 0.33262347f;
  p = p*t2 + 0.99997726f;
  float r = t*p;
  r = inv ? 1.5707963267948966f - r : r;
  return copysignf(r,x);
}
static __device__ __forceinline__ float ftan(float x){
  x = fminf(fmaxf(x,-TANC),TANC);
  float r = x*0.15915494309189535f;
  float s = __builtin_amdgcn_sinf(r);
  float c = __builtin_amdgcn_cosf(r);
  return s*frcp(c);
}
static __device__ __forceinline__ float sigm(float x){ return frcp(1.0f+fexp(-x)); }
static __device__ __forceinline__ float safeden(float d){
  return d>=0.0f ? fmaxf(d,EPSF) : fminf(d,-EPSF);
}

static __device__ __forceinline__ float wred(float v){
#pragma unroll
  for(int m=32;m;m>>=1) v += __shfl_xor(v,m,64);
  return v;
}
static __device__ __forceinline__ float hred16(float v){
#pragma unroll
  for(int m=8;m;m>>=1) v += __shfl_xor(v,m,64);
  return v;
}

// ---------- f16 helpers ----------
static __device__ __forceinline__ f32x2 ldh2(const u16* p){
  f16x2 v = *(const f16x2*)p;
  return (f32x2){(float)v[0], (float)v[1]};
}
static __device__ __forceinline__ void sth2(u16* p, float a, float b){
  *(f16x2*)p = (f16x2){(f16)a, (f16)b};
}

// ---------------- workspace layout ----------------
// planes 0-8:  f16 A inputs (k_pre); planes 0-6 later reused for f16 Y planes (B-GEMM out)
// planes 9-17: f16 gemmA outputs S1..S3,F1..F3,Q1..Q3; 9-11 later overwritten by f16 LP/LS/LE,
//              12-14 later overwritten by f16 C1o..C3o
// planes 18-20: f16 XP,XS,XE
// planes 21-26: f16 consumer-grouped gather planes:
//   PKP @21, PKS @22, PKE @23: [node][64] f16x2 ; PKV4 @24: [node][64] f16x4 ; PKV2 @26: [node][64] f16x2
// SCOFF: SC4[node] = {y2p,y2s,d1,d2} f32, then c1n2 @+32768, c2n2 @+40960
#define SCOFF (27*NHS)
#define WOFF  (27*NHS + 49152)
#define NW    114688

// ---------------- kernel 1: weight convert + per-row pre-transforms (fused) ----------------
__global__ __launch_bounds__(256) void k_pre(
    const float* __restrict__ x, const float* __restrict__ h1,
    const float* __restrict__ h2, const float* __restrict__ c1,
    const float* __restrict__ c2, const float* __restrict__ h3,
    const float* __restrict__ c3,
    const float* __restrict__ Wq, const float* __restrict__ Wc,
    const float* __restrict__ Uf, const float* __restrict__ Up,
    const float* __restrict__ Uiou, float* __restrict__ ws)
{
  if(blockIdx.x >= 2048){
    // ---- weight f16 convert ----
    u16* WH = (u16*)(ws + WOFF);
    int idx0 = ((blockIdx.x-2048)*256 + threadIdx.x)*4;
#pragma unroll
    for(int q=0;q<4;q+=2){
      int idx = idx0 + q;
      float v0, v1;
      if(idx < 16384)      { v0=Wq[idx]; v1=Wq[idx+1]; }
      else if(idx < 32768) { v0=Wc[idx-16384]; v1=Wc[idx-16383]; }
      else if(idx < 49152) { v0=Uf[idx-32768]; v1=Uf[idx-32767]; }
      else if(idx < 65536) { v0=Up[idx-49152]; v1=Up[idx-49151]; }
      else                 { v0=Uiou[idx-65536]; v1=Uiou[idx-65535]; }
      sth2(&WH[idx], v0, v1);
    }
    return;
  }
  int row = blockIdx.x*4 + (threadIdx.x>>6);
  int l = threadIdx.x & 63;
  size_t i0 = (size_t)row*HD + 2*l;
#define LD2(p) (*(const f32x2*)&p[i0])
  f32x2 xv = LD2(x);
  f32x2 h1v = LD2(h1), h2v = LD2(h2), h3v = LD2(h3);
  f32x2 c1v = LD2(c1), c2v = LD2(c2), c3v = LD2(c3);
#undef LD2
  float xa=xv[0], xb=xv[1];
  float h1a=h1v[0], h1b=h1v[1];
  float h2a=h2v[0], h2b=h2v[1];
  float c1a=c1v[0], c1b=c1v[1];
  float c2a=c2v[0], c2b=c2v[1];
  float h3a=h3v[0], h3b=h3v[1];
  float c3a=c3v[0], c3b=c3v[1];
  float xsq = wred(xa*xa+xb*xb);
  float h1sq = wred(h1a*h1a+h1b*h1b);
  float h2sq = wred(h2a*h2a+h2b*h2b);
  float c1sq = wred(c1a*c1a+c1b*c1b);
  float c2sq = wred(c2a*c2a+c2b*c2b);
  size_t p0 = i0;
#define WRF16(R, va, vb) sth2(&((u16*)(ws + (size_t)(R)*NHS))[p0], va, vb);
  float nx = fsqrt(xsq+1e-15f);
  {
    float t = ftanh(nx);
    float f = fminf(t,PMX)*frcp(nx);
    float ny = fsqrt(f*f*xsq + 1e-15f);
    float g = fatanh(ny)*frcp(ny) * f;
    WRF16(0, g*xa, g*xb)
  }
  {
    float t = ftan(nx);
    float f = t*frcp(nx);
    float ny = fsqrt(f*f*xsq + 1e-15f);
    float g = fatan(ny)*frcp(ny) * f;
    WRF16(1, g*xa, g*xb)
  }
  WRF16(2, xa, xb)
  { float n=fsqrt(h1sq+1e-15f); float g=fatanh(n)*frcp(n); WRF16(3, g*h1a, g*h1b) }
  { float n=fsqrt(h2sq+1e-15f); float g=fatan(n)*frcp(n);  WRF16(4, g*h2a, g*h2b) }
  WRF16(5, h3a, h3b)
  { float n=fsqrt(c1sq+1e-15f); float g=fatanh(n)*frcp(n); WRF16(6, g*c1a, g*c1b) }
  { float n=fsqrt(c2sq+1e-15f); float g=fatan(n)*frcp(n);  WRF16(7, g*c2a, g*c2b) }
  WRF16(8, c3a, c3b)
#undef WRF16
}

// ---------------- MFMA f16 single-pass GEMM with LDS-staged W, f16 output ----------------
enum { P_ID=0, P_EXP_P, P_EXP_S, P_SIG, P_TANH, P_SIG_LOG_P, P_SIG_LOG_S,
       P_LOGSIG_P, P_LOGSIG_S, P_TANH_EXP_P, P_TANH_EXP_S };

struct JobM { const u16* A; const u16* W; const float* b; u16* out; int pitch; int post; };
struct JobTabM { JobM j[12]; };

// 512 threads = 8 waves; each wave owns a 16-row strip -> 128 rows per block.
// LDS 32KB. R6 configuration == best measured (227.1us); R7 (256thr), R8 (lazy norm),
// R9 (transposed epilogue) all null or regressed — keep this geometry.
__global__ __launch_bounds__(512) void k_gemmM(JobTabM tab){
  JobM jb = tab.j[blockIdx.y];
  __shared__ u16 Wlds[8*4*64*8];   // 32 KB, fragment-contiguous
  const int tid = threadIdx.x;
  const int lane = tid & 63;
  const int wave = tid >> 6;   // 0..7
  const int nn = lane & 15, quad = lane >> 4;
  const int row0 = blockIdx.x*128 + wave*16;
  // ---- prefetch A fragments FIRST (latency overlaps W staging) ----
  const u16* A = jb.A + (size_t)(row0+nn)*128 + quad*8;
  f16x8 a[4];
#pragma unroll
  for(int kk=0;kk<4;kk++) a[kk] = *(const f16x8*)(A + kk*32);
  // ---- stage W into LDS in fragment order ----
  for(int c = tid; c < 2048; c += 512){
    int lane_ = c & 63;
    int kk    = (c>>6)&3;
    int t     = (c>>8)&7;
    const u16* src = jb.W + (size_t)(t*16 + (lane_&15))*128 + (lane_>>4)*8 + kk*32;
    *(uint4*)&Wlds[(size_t)c*8] = *(const uint4*)src;
  }
  float bias[8];
#pragma unroll
  for(int t=0;t<8;t++) bias[t] = jb.b[t*16+nn];
  __syncthreads();
  {
    f32x4 acc[8];
#pragma unroll
    for(int t=0;t<8;t++) acc[t] = (f32x4){0.f,0.f,0.f,0.f};
#pragma unroll
    for(int kk=0;kk<4;kk++){
#pragma unroll
      for(int t=0;t<8;t++){
        f16x8 wh = *(const f16x8*)&Wlds[((t*4 + kk)*64 + lane)*8];
        acc[t] = __builtin_amdgcn_mfma_f32_16x16x32_f16(a[kk], wh, acc[t], 0,0,0);
      }
    }
#pragma unroll
    for(int r=0;r<4;r++){
      float v[8];
#pragma unroll
      for(int t=0;t<8;t++) v[t] = acc[t][r] + bias[t];
      float s2 = 0.f;
#pragma unroll
      for(int t=0;t<8;t++) s2 += v[t]*v[t];
      float nraw = hred16(s2);
      switch(jb.post){
        case P_ID: break;
        case P_EXP_P: {
          float n=fsqrt(nraw+1e-15f); float tt=ftanh(n); float f=fminf(tt,PMX)*frcp(n);
          for(int t=0;t<8;t++) v[t]*=f;
        } break;
        case P_EXP_S: {
          float n=fsqrt(nraw+1e-15f); float f=ftan(n)*frcp(n);
          for(int t=0;t<8;t++) v[t]*=f;
        } break;
        case P_SIG:
          for(int t=0;t<8;t++) v[t]=sigm(v[t]);
          break;
        case P_TANH:
          for(int t=0;t<8;t++) v[t]=ftanh(v[t]);
          break;
        case P_SIG_LOG_P: {
          float n=fsqrt(nraw+1e-15f); float tt=ftanh(n); float f=fminf(tt,PMX)*frcp(n);
          float z[8]; float zs=0.f;
          for(int t=0;t<8;t++){ z[t]=sigm(f*v[t]); zs+=z[t]*z[t]; }
          float zr=hred16(zs);
          float zn=fsqrt(zr+1e-15f);
          float g=fatanh(zn)*frcp(zn);
          for(int t=0;t<8;t++) v[t]=g*z[t];
        } break;
        case P_SIG_LOG_S: {
          float n=fsqrt(nraw+1e-15f); float f=ftan(n)*frcp(n);
          float z[8]; float zs=0.f;
          for(int t=0;t<8;t++){ z[t]=sigm(f*v[t]); zs+=z[t]*z[t]; }
          float zr=hred16(zs);
          float zn=fsqrt(zr+1e-15f);
          float g=fatan(zn)*frcp(zn);
          for(int t=0;t<8;t++) v[t]=g*z[t];
        } break;
        case P_LOGSIG_P: {
          float n=fsqrt(nraw+1e-15f); float tt=ftanh(n); float f=fminf(tt,PMX)*frcp(n);
          float ny=fsqrt(f*f*nraw+1e-15f);
          float g=fatanh(ny)*frcp(ny)*f;
          for(int t=0;t<8;t++) v[t]=sigm(g*v[t]);
        } break;
        case P_LOGSIG_S: {
          float n=fsqrt(nraw+1e-15f); float f=ftan(n)*frcp(n);
          float ny=fsqrt(f*f*nraw+1e-15f);
          float g=fatan(ny)*frcp(ny)*f;
          for(int t=0;t<8;t++) v[t]=sigm(g*v[t]);
        } break;
        case P_TANH_EXP_P: {
          float n=fsqrt(nraw+1e-15f); float tt=ftanh(n); float f=fminf(tt,PMX)*frcp(n);
          float ny=fsqrt(f*f*nraw+1e-15f);
          float g=fatanh(ny)*frcp(ny)*f;
          float T[8]; float Ts=0.f;
          for(int t=0;t<8;t++){ T[t]=ftanh(g*v[t]); Ts+=T[t]*T[t]; }
          float Tr=hred16(Ts);
          float Tn=fsqrt(Tr+1e-15f);
          float t2=ftanh(Tn); float f2=fminf(t2,PMX)*frcp(Tn);
          for(int t=0;t<8;t++) v[t]=f2*T[t];
        } break;
        case P_TANH_EXP_S: {
          float n=fsqrt(nraw+1e-15f); float f=ftan(n)*frcp(n);
          float ny=fsqrt(f*f*nraw+1e-15f);
          float g=fatan(ny)*frcp(ny)*f;
          float T[8]; float Ts=0.f;
          for(int t=0;t<8;t++){ T[t]=ftanh(g*v[t]); Ts+=T[t]*T[t]; }
          float Tr=hred16(Ts);
          float Tn=fsqrt(Tr+1e-15f);
          float f2=ftan(Tn)*frcp(Tn);
          for(int t=0;t<8;t++) v[t]=f2*T[t];
        } break;
      }
      u16* orow = jb.out + (size_t)(row0 + quad*4 + r)*jb.pitch + nn;
#pragma unroll
      for(int t=0;t<8;t++) *(f16*)&orow[t*16] = (f16)v[t];
    }
  }
}

// ---------------- kernel 3: per-unique-node elementwise (phase B) ----------------
__global__ __launch_bounds__(256) void k_phaseB(
  const float* __restrict__ h1,const float* __restrict__ h2,const float* __restrict__ h3,
  const float* __restrict__ c1,const float* __restrict__ c2,const float* __restrict__ c3,
  const float* __restrict__ del_t, const float* __restrict__ dsc,
  float* __restrict__ ws)
{
  const u16* S1 = (const u16*)(ws+9*NHS);  const u16* S2 = (const u16*)(ws+10*NHS);
  const u16* S3 = (const u16*)(ws+11*NHS); const u16* F1 = (const u16*)(ws+12*NHS);
  const u16* F2 = (const u16*)(ws+13*NHS); const u16* F3 = (const u16*)(ws+14*NHS);
  const u16* Q1 = (const u16*)(ws+15*NHS); const u16* Q2 = (const u16*)(ws+16*NHS);
  const u16* Q3 = (const u16*)(ws+17*NHS);
  f16x2* PKP = (f16x2*)(ws+21*NHS);
  f16x2* PKS = (f16x2*)(ws+22*NHS);
  f16x2* PKE = (f16x2*)(ws+23*NHS);
  f16x4* PKV4= (f16x4*)(ws+24*NHS);
  f16x2* PKV2= (f16x2*)(ws+26*NHS);
  f32x4* SC4 = (f32x4*)(ws+SCOFF);

  int j = blockIdx.x*4 + (threadIdx.x>>6);
  int l = threadIdx.x&63;
  size_t i0 = (size_t)j*HD + 2*l;
  size_t pix = (size_t)j*64 + l;
#define LD2(p) (*(const f32x2*)&p[i0])
  f32x2 h1v=LD2(h1), h2v=LD2(h2), h3v=LD2(h3);
  f32x2 c1v=LD2(c1), c2v=LD2(c2), c3v=LD2(c3);
#undef LD2
  f32x2 s1v=ldh2(&S1[i0]), s2v=ldh2(&S2[i0]), s3v=ldh2(&S3[i0]);
  f32x2 f1v=ldh2(&F1[i0]), f2v=ldh2(&F2[i0]), f3v=ldh2(&F3[i0]);
  f32x2 q1v=ldh2(&Q1[i0]), q2v=ldh2(&Q2[i0]), q3v=ldh2(&Q3[i0]);
  float h1a=h1v[0],h1b=h1v[1], h2a=h2v[0],h2b=h2v[1], h3a=h3v[0],h3b=h3v[1];
  float c1a=c1v[0],c1b=c1v[1], c2a=c2v[0],c2b=c2v[1], c3a=c3v[0],c3b=c3v[1];
  float s1a=s1v[0],s1b=s1v[1], s2a=s2v[0],s2b=s2v[1], s3a=s3v[0],s3b=s3v[1];
  float f1a=f1v[0],f1b=f1v[1], f2a=f2v[0],f2b=f2v[1], f3a=f3v[0],f3b=f3v[1];
  float q1a=q1v[0],q1b=q1v[1], q2a=q2v[0],q2b=q2v[1], q3a=q3v[0],q3b=q3v[1];
  float g = fdiv(dsc[0], del_t[j]+1.0f);

  float h1sq = wred(h1a*h1a+h1b*h1b); float n1 = fsqrt(h1sq+1e-15f);
  float h2sq = wred(h2a*h2a+h2b*h2b); float n2 = fsqrt(h2sq+1e-15f);
  float h3sq = wred(h3a*h3a+h3b*h3b); float n3 = fsqrt(h3sq+1e-15f);
  float w1a=s1a*h1a, w1b=s1b*h1b;
  float w2a=s2a*h2a, w2b=s2b*h2b;
  float w3a=s3a*h3a, w3b=s3b*h3b;
  float w1sq = wred(w1a*w1a+w1b*w1b); float nw1 = fsqrt(w1sq+1e-15f);
  float w2sq = wred(w2a*w2a+w2b*w2b); float nw2 = fsqrt(w2sq+1e-15f);
  float w3sq = wred(w3a*w3a+w3b*w3b); float nw3 = fsqrt(w3sq+1e-15f);

  // ---- h_1p
  float t1 = ftanh(nw1*frcp(n1) * fatanh(n1));
  float fp1 = fminf(t1,PMX)*frcp(nw1); float np1 = fminf(t1,PMX);
  float nu2 = fatan(n2);
  float ne2 = fminf(ftanh(nu2),PMX);
  float t2 = ftanh(nw2*frcp(n2) * fatanh(ne2));
  float fp2 = fminf(t2,PMX)*frcp(nw2); float np2 = fminf(t2,PMX);
  float ne3 = fminf(ftanh(n3),PMX);
  float t3 = ftanh(nw3*frcp(n3) * fatanh(ne3));
  float fp3 = fminf(t3,PMX)*frcp(nw3); float np3 = fminf(t3,PMX);
  float y2pv;
  {
    float lamA = 2.0f*frcp(1.0f-np1*np1), lamB = 2.0f*frcp(1.0f-np2*np2), lamC = 2.0f*frcp(1.0f-np3*np3);
    float dn = frcp(fmaxf(fabsf(lamA+lamB+lamC-3.0f), EPSF));
    float va = (lamA*fp1*w1a + lamB*fp2*w2a + lamC*fp3*w3a)*dn;
    float vb = (lamA*fp1*w1b + lamB*fp2*w2b + lamC*fp3*w3b)*dn;
    float vsq = wred(va*va+vb*vb); float nv = fsqrt(vsq+1e-15f);
    float tt = ftanh(0.5f*fatanh(nv)); float ff = 3.0f*fminf(tt,PMX)*frcp(nv);
    PKP[pix] = (f16x2){(f16)(ff*va), (f16)(ff*vb)};
    y2pv = ff*ff*vsq;
  }
  // ---- h_1s
  float t2s, fs2, y2sv;
  {
    float nx1s = ftan(fatanh(n1));
    float t1s = ftanh(nw1*frcp(n1) * fatanh(nx1s));
    float fs1 = fminf(t1s,PMX)*frcp(nw1); float ns1 = fminf(t1s,PMX);
    t2s = ftan(nw2*frcp(n2) * fatan(n2));
    fs2 = t2s*frcp(nw2);
    float nx3s = ftan(n3);
    float t3s = ftan(nw3*frcp(n3) * fatan(nx3s));
    float fs3 = t3s*frcp(nw3);
    float lA = 2.0f*frcp(1.0f-ns1*ns1), lB = 2.0f*frcp(1.0f-t2s*t2s), lC = 2.0f*frcp(1.0f-t3s*t3s);
    float dns = frcp(fmaxf(fabsf(lA+lB+lC-3.0f), EPSF));
    float vsa = (lA*fs1*w1a + lB*fs2*w2a + lC*fs3*w3a)*dns;
    float vsb = (lA*fs1*w1b + lB*fs2*w2b + lC*fs3*w3b)*dns;
    float vssq = wred(vsa*vsa+vsb*vsb); float nvs = fsqrt(vssq+1e-15f);
    float tts = ftan(0.5f*fatan(nvs)); float ffs = 3.0f*tts*frcp(nvs);
    PKS[pix] = (f16x2){(f16)(ffs*vsa), (f16)(ffs*vsb)};
    y2sv = ffs*ffs*vssq;
  }
  // ---- h_1e
  {
    float ne1 = fsqrt(fp1*fp1*w1sq + 1e-15f);
    float ge1 = fatanh(ne1)*frcp(ne1);
    float n2s_ = fsqrt(fs2*fs2*w2sq + 1e-15f);
    float ge2 = fatan(n2s_)*frcp(n2s_);
    float h1ea = ge1*fp1*w1a + ge2*fs2*w2a + s3a*h3a;
    float h1eb = ge1*fp1*w1b + ge2*fs2*w2b + s3b*h3b;
    PKE[pix] = (f16x2){(f16)h1ea, (f16)h1eb};
  }
  float ng = fsqrt(g*g+1e-15f);
  // ---- Poincare cell
  float v1xa,v1xb,d1v;
  {
    float q1sq = wred(q1a*q1a+q1b*q1b);
    float c1rs = wred(c1a*c1a+c1b*c1b);
    float dq1 = wred(q1a*c1a+q1b*c1b);
    float xy = -dq1;
    float aa = 1.0f+2.0f*xy+c1rs, bb = 1.0f-q1sq;
    float dd = frcp(safeden(1.0f+2.0f*xy+q1sq*c1rs));
    float m1a = (aa*(-q1a)+bb*c1a)*dd, m1b = (aa*(-q1b)+bb*c1b)*dd;
    float m1sq = (aa*aa*q1sq + 2.0f*aa*bb*xy + bb*bb*c1rs)*dd*dd;
    float mdq = (-aa*q1sq + bb*dq1)*dd;
    { float nm = fsqrt(m1sq+1e-15f);
      if(nm>PMX){ float sc=PMX*frcp(nm); m1a*=sc; m1b*=sc; m1sq*=sc*sc; mdq*=sc; } }
    float nwg = fsqrt(g*g*q1sq+1e-15f);
    float tg = ftanh(nwg*frcp(ng) * fatanh(ng));
    float fX = fminf(tg,PMX)*frcp(nwg) * g;
    float X2sq = fX*fX*q1sq;
    float xy2 = fX*mdq;
    float a2 = 1.0f+2.0f*xy2+X2sq, b2 = 1.0f-m1sq;
    float d2d = frcp(safeden(1.0f+2.0f*xy2+m1sq*X2sq));
    float ka = (a2*m1a + b2*fX*q1a)*d2d, kb = (a2*m1b + b2*fX*q1b)*d2d;
    float ksq = (a2*a2*m1sq + 2.0f*a2*b2*xy2 + b2*b2*X2sq)*d2d*d2d;
    { float nk0 = fsqrt(ksq+1e-15f);
      if(nk0>PMX){ float sc=PMX*frcp(nk0); ka*=sc; kb*=sc; ksq*=sc*sc; } }
    float nk = fsqrt(ksq+1e-15f);
    float wfa = f1a*ka, wfb = f1b*kb;
    float wfsq = wred(wfa*wfa+wfb*wfb); float nwf = fsqrt(wfsq+1e-15f);
    float tu = ftanh(nwf*frcp(nk) * fatanh(nk));
    float fu = fminf(tu,PMX)*frcp(nwf);
    float u1sq = fu*fu*wfsq;
    float lam = 2.0f*frcp(1.0f-u1sq);
    v1xa=lam*fu*wfa; v1xb=lam*fu*wfb;
    d1v=lam-1.0f;
  }
  // ---- Sphere cell
  float v2xa,v2xb,d2v;
  {
    float q2sq = wred(q2a*q2a+q2b*q2b);
    float c2rs = wred(c2a*c2a+c2b*c2b);
    float dq2 = wred(q2a*c2a+q2b*c2b);
    float xy = -dq2;
    float aa = 1.0f-2.0f*xy-c2rs, bb = 1.0f+q2sq;
    float dd = frcp(safeden(1.0f-2.0f*xy+q2sq*c2rs));
    float ma = (aa*(-q2a)+bb*c2a)*dd, mb = (aa*(-q2b)+bb*c2b)*dd;
    float msq = (aa*aa*q2sq + 2.0f*aa*bb*xy + bb*bb*c2rs)*dd*dd;
    float mdq = (-aa*q2sq + bb*dq2)*dd;
    float nwg = fsqrt(g*g*q2sq+1e-15f);
    float tg = ftan(nwg*frcp(ng) * fatan(ng));
    float fX = tg*frcp(nwg) * g;
    float X2sq = fX*fX*q2sq;
    float xy2 = fX*mdq;
    float a2 = 1.0f-2.0f*xy2-X2sq, b2 = 1.0f+msq;
    float d2d = frcp(safeden(1.0f-2.0f*xy2+msq*X2sq));
    float ka = (a2*ma + b2*fX*q2a)*d2d, kb = (a2*mb + b2*fX*q2b)*d2d;
    float ksq = (a2*a2*msq + 2.0f*a2*b2*xy2 + b2*b2*X2sq)*d2d*d2d;
    float nk = fsqrt(ksq+1e-15f);
    float wfa = f2a*ka, wfb = f2b*kb;
    float wfsq = wred(wfa*wfa+wfb*wfb); float nwf = fsqrt(wfsq+1e-15f);
    float tu = ftan(nwf*frcp(nk) * fatan(nk));
    float fu = tu*frcp(nwf);
    float u2sq = fu*fu*wfsq;
    float lam = 2.0f*frcp(1.0f+u2sq);
    v2xa=lam*fu*wfa; v2xb=lam*fu*wfb;
    d2v=lam-1.0f;
  }
  // ---- Euclid cell
  float v3xa,v3xb;
  {
    float kea = c3a + q3a*(g-1.0f), keb = c3b + q3b*(g-1.0f);
    v3xa=f3a*kea; v3xb=f3b*keb;
  }
  PKV4[pix] = (f16x4){(f16)v1xa,(f16)v1xb,(f16)v2xa,(f16)v2xb};
  PKV2[pix] = (f16x2){(f16)v3xa,(f16)v3xb};
  if(l==0) SC4[j] = (f32x4){y2pv,y2sv,d1v,d2v};
}

// ---------------- kernel 4: attention + K-reductions (4 specialized waves per node) ----------------
__global__ __launch_bounds__(256) void k_attn(
  const int* __restrict__ nbr, float* __restrict__ ws)
{
  const f16x2* PKP = (const f16x2*)(ws+21*NHS);
  const f16x2* PKS = (const f16x2*)(ws+22*NHS);
  const f16x2* PKE = (const f16x2*)(ws+23*NHS);
  const f16x4* PKV4= (const f16x4*)(ws+24*NHS);
  const f16x2* PKV2= (const f16x2*)(ws+26*NHS);
  const float* SCf = ws+SCOFF;
  u16* LP = (u16*)(ws+9*NHS);
  u16* LS = (u16*)(ws+10*NHS);
  u16* LE = (u16*)(ws+11*NHS);
  u16* C1o = (u16*)(ws+12*NHS); u16* C2o = (u16*)(ws+13*NHS); u16* C3o = (u16*)(ws+14*NHS);
  float* c1n2 = ws+SCOFF+32768; float* c2n2 = ws+SCOFF+40960;

  int n = blockIdx.x;
  int wv = threadIdx.x>>6;
  int l = threadIdx.x&63;
  size_t i0 = (size_t)n*HD + 2*l;
  int4 jA = ((const int4*)nbr)[n*2+0];
  int4 jB = ((const int4*)nbr)[n*2+1];
  int js[8] = {jA.x,jA.y,jA.z,jA.w,jB.x,jB.y,jB.z,jB.w};

  if(wv==0){
    // ---- Poincare attention ----
    const u16* XP = (const u16*)(ws+18*NHS);
    f32x2 xv = ldh2(&XP[i0]);
    float XPa=xv[0], XPb=xv[1];
    float x2p = wred(XPa*XPa+XPb*XPb);
    float Ha[8],Hb[8],y2k[8];
#pragma unroll
    for(int k=0;k<8;k++){
      int j = js[k];
      f16x2 h = PKP[(size_t)j*64+l];
      Ha[k]=(float)h[0]; Hb[k]=(float)h[1];
      y2k[k]=SCf[(size_t)j*4+0];
    }
    float sc[8];
#pragma unroll
    for(int k=0;k<8;k++){
      float dp = wred(XPa*Ha[k]+XPb*Hb[k]);
      float xy=-dp, y2=y2k[k];
      float aa=1.0f+2.0f*xy+y2, bb=1.0f-x2p;
      float dd=frcp(safeden(1.0f+2.0f*xy+x2p*y2));
      float nsq=(aa*aa*x2p+2.0f*aa*bb*xy+bb*bb*y2)*dd*dd;
      float nn=fminf(fsqrt(nsq+1e-15f),PMX);
      sc[k] = -2.0f*fatanh(nn);
    }
    float mx=sc[0];
#pragma unroll
    for(int k=1;k<8;k++) mx=fmaxf(mx,sc[k]);
    float a[8]; float s=0;
#pragma unroll
    for(int k=0;k<8;k++){ a[k]=fexp(sc[k]-mx); s+=a[k]; }
    float inv=frcp(s);
    float na=0,nb=0,de=0;
#pragma unroll
    for(int k=0;k<8;k++){
      float lam = 2.0f*frcp(1.0f-y2k[k]); float w=a[k]*inv;
      na+=w*lam*Ha[k]; nb+=w*lam*Hb[k]; de+=w*(lam-1.0f);
    }
    de = frcp(fmaxf(fabsf(de),EPSF));
    na*=de; nb*=de;
    float vsq=wred(na*na+nb*nb); float nv=fsqrt(vsq+1e-15f);
    float tt=ftanh(0.5f*fatanh(nv)); float f=fminf(tt,PMX)*frcp(nv);
    float ha=f*na, hb=f*nb;
    float hn=fsqrt(f*f*vsq+1e-15f);
    float gl=fatanh(hn)*frcp(hn);
    sth2(&LP[i0], gl*ha, gl*hb);
  } else if(wv==1){
    // ---- Sphere attention ----
    const u16* XS = (const u16*)(ws+19*NHS);
    f32x2 xv = ldh2(&XS[i0]);
    float XSa=xv[0], XSb=xv[1];
    float x2s = wred(XSa*XSa+XSb*XSb);
    float Ha[8],Hb[8],y2k[8];
#pragma unroll
    for(int k=0;k<8;k++){
      int j = js[k];
      f16x2 h = PKS[(size_t)j*64+l];
      Ha[k]=(float)h[0]; Hb[k]=(float)h[1];
      y2k[k]=SCf[(size_t)j*4+1];
    }
    float sc[8];
#pragma unroll
    for(int k=0;k<8;k++){
      float dsv = wred(XSa*Ha[k]+XSb*Hb[k]);
      float xy=-dsv, y2=y2k[k];
      float aa=1.0f-2.0f*xy-y2, bb=1.0f+x2s;
      float dd=frcp(safeden(1.0f-2.0f*xy+x2s*y2));
      float nsq=(aa*aa*x2s+2.0f*aa*bb*xy+bb*bb*y2)*dd*dd;
      float nn=fsqrt(nsq+1e-15f);
      sc[k] = -2.0f*fatan(nn);
    }
    float mx=sc[0];
#pragma unroll
    for(int k=1;k<8;k++) mx=fmaxf(mx,sc[k]);
    float a[8]; float s=0;
#pragma unroll
    for(int k=0;k<8;k++){ a[k]=fexp(sc[k]-mx); s+=a[k]; }
    float inv=frcp(s);
    float na=0,nb=0,de=0;
#pragma unroll
    for(int k=0;k<8;k++){
      float lam = 2.0f*frcp(1.0f+y2k[k]); float w=a[k]*inv;
      na+=w*lam*Ha[k]; nb+=w*lam*Hb[k]; de+=w*(lam-1.0f);
    }
    de = frcp(fmaxf(fabsf(de),EPSF));
    na*=de; nb*=de;
    float vsq=wred(na*na+nb*nb); float nv=fsqrt(vsq+1e-15f);
    float tt=ftan(0.5f*fatan(nv)); float f=tt*frcp(nv);
    float ha=f*na, hb=f*nb;
    float hn=fsqrt(f*f*vsq+1e-15f);
    float gl=fatan(hn)*frcp(hn);
    sth2(&LS[i0], gl*ha, gl*hb);
  } else if(wv==2){
    // ---- Euclid attention ----
    const u16* XE = (const u16*)(ws+20*NHS);
    const float rs = 0.08838834764831845f;
    f32x2 xv = ldh2(&XE[i0]);
    float XEa=xv[0], XEb=xv[1];
    float Ha[8],Hb[8];
#pragma unroll
    for(int k=0;k<8;k++){
      int j = js[k];
      f16x2 h = PKE[(size_t)j*64+l];
      Ha[k]=(float)h[0]; Hb[k]=(float)h[1];
    }
    float sc[8];
#pragma unroll
    for(int k=0;k<8;k++) sc[k] = wred(XEa*Ha[k]+XEb*Hb[k])*rs;
    float mx=sc[0];
#pragma unroll
    for(int k=1;k<8;k++) mx=fmaxf(mx,sc[k]);
    float a[8]; float s=0;
#pragma unroll
    for(int k=0;k<8;k++){ a[k]=fexp(sc[k]-mx); s+=a[k]; }
    float inv=frcp(s);
    float ha=0,hb=0;
#pragma unroll
    for(int k=0;k<8;k++){ float w=a[k]*inv; ha+=w*Ha[k]; hb+=w*Hb[k]; }
    sth2(&LE[i0], ha, hb);
  } else {
    // ---- cell-path V sums + outputs ----
    float v1a=0,v1b=0,v2a=0,v2b=0,v3a=0,v3b=0,ds1=0,ds2=0;
#pragma unroll
    for(int k=0;k<8;k++){
      int j = js[k];
      f16x4 v4 = PKV4[(size_t)j*64+l];
      f16x2 v2 = PKV2[(size_t)j*64+l];
      v1a+=(float)v4[0]; v1b+=(float)v4[1]; v2a+=(float)v4[2]; v2b+=(float)v4[3];
      v3a+=(float)v2[0]; v3b+=(float)v2[1];
      ds1+=SCf[(size_t)j*4+2]; ds2+=SCf[(size_t)j*4+3];
    }
    { // c_1
      float de=frcp(fmaxf(fabsf(ds1),EPSF));
      float na=v1a*de, nb=v1b*de;
      float vsq=wred(na*na+nb*nb); float nv=fsqrt(vsq+1e-15f);
      float tt=ftanh(0.5f*fatanh(nv)); float f=fminf(tt,PMX)*frcp(nv);
      sth2(&C1o[i0], f*na, f*nb);
      if(l==0) c1n2[n]=f*f*vsq;
    }
    { // c_2
      float de=frcp(fmaxf(fabsf(ds2),EPSF));
      float na=v2a*de, nb=v2b*de;
      float vsq=wred(na*na+nb*nb); float nv=fsqrt(vsq+1e-15f);
      float tt=ftan(0.5f*fatan(nv)); float f=tt*frcp(nv);
      sth2(&C2o[i0], f*na, f*nb);
      if(l==0) c2n2[n]=f*f*vsq;
    }
    sth2(&C3o[i0], v3a, v3b);
  }
}

// ---------------- kernel 6: final epilogue ----------------
__global__ __launch_bounds__(256) void k_final(
  const float* __restrict__ iou1, const float* __restrict__ iou2,
  const float* __restrict__ iou3, float* __restrict__ ws,
  float* __restrict__ out)
{
  const u16* YP = (const u16*)ws;
  const u16* YS = (const u16*)(ws+3*NHS);
  const u16* YE = (const u16*)(ws+6*NHS);
  const u16* C1v = (const u16*)(ws+12*NHS);
  const u16* C2v = (const u16*)(ws+13*NHS);
  const u16* C3v = (const u16*)(ws+14*NHS);
  const float* c1n2 = ws+SCOFF+32768; const float* c2n2 = ws+SCOFF+40960;
  int n = blockIdx.x*4 + (threadIdx.x>>6);
  int l = threadIdx.x&63;
  size_t b384 = (size_t)n*384 + 2*l;
  size_t b128 = (size_t)n*HD + 2*l;
  // ================= Poincare =================
  {
    float Y[6], I[6];
#pragma unroll
    for(int p=0;p<3;p++){
      f32x2 yv = ldh2(&YP[b384 + 128*p]);
      f32x2 iv = *(const f32x2*)&iou1[b384 + 128*p];
      Y[2*p]=yv[0]; Y[2*p+1]=yv[1]; I[2*p]=iv[0]; I[2*p+1]=iv[1];
    }
    float sy=0,si=0,sx=0;
#pragma unroll
    for(int r=0;r<6;r++){ sy+=Y[r]*Y[r]; si+=I[r]*I[r]; sx+=I[r]*Y[r]; }
    sy=wred(sy); si=wred(si); sx=wred(sx);
    float nY=fsqrt(sy+1e-15f);
    float te=ftanh(nY); float fE=fminf(te,PMX)*frcp(nY);
    float y2=fE*fE*sy, x2=si, xy=fE*sx;
    float aa=1.0f+2.0f*xy+y2, bb=1.0f-x2;
    float dd=frcp(safeden(1.0f+2.0f*xy+x2*y2));
    float nio[6];
#pragma unroll
    for(int r=0;r<6;r++) nio[r]=(aa*I[r]+bb*fE*Y[r])*dd;
    float nsq=(aa*aa*x2+2.0f*aa*bb*xy+bb*bb*y2)*dd*dd;
    { float nn=fsqrt(nsq+1e-15f);
      if(nn>PMX){ float sc=PMX*frcp(nn); for(int r=0;r<6;r++) nio[r]*=sc; } }
    float ci=wred(nio[0]*nio[0]+nio[1]*nio[1]); float ni=fsqrt(ci+1e-15f); float gi=fatanh(ni)*frcp(ni);
    float ip0=sigm(gi*nio[0]), ip1=sigm(gi*nio[1]);
    float co=wred(nio[2]*nio[2]+nio[3]*nio[3]); float no=fsqrt(co+1e-15f); float go=fatanh(no)*frcp(no);
    float op0=sigm(go*nio[2]), op1=sigm(go*nio[3]);
    float cu=wred(nio[4]*nio[4]+nio[5]*nio[5]); float nu=fsqrt(cu+1e-15f); float gu=fatanh(nu)*frcp(nu);
    float up0=ftanh(gu*nio[4]), up1=ftanh(gu*nio[5]);
    float usq=wred(up0*up0+up1*up1); float nx=fsqrt(usq+1e-15f);
    float wv0=ip0*up0, wv1=ip1*up1;
    float wsq=wred(wv0*wv0+wv1*wv1); float nwx=fsqrt(wsq+1e-15f);
    float tP=ftanh(nwx*frcp(nx)*fatanh(nx)); float fP=fminf(tP,PMX)*frcp(nwx);
    float P0=fP*wv0, P1=fP*wv1; float p2=fP*fP*wsq;
    f32x2 cv = ldh2(&C1v[b128]);
    float ca=cv[0], cb=cv[1];
    float y2c=c1n2[n];
    float xyc=wred(P0*ca+P1*cb);
    float a3=1.0f+2.0f*xyc+y2c, b3=1.0f-p2;
    float d3=frcp(safeden(1.0f+2.0f*xyc+p2*y2c));
    float nc0=(a3*P0+b3*ca)*d3, nc1_=(a3*P1+b3*cb)*d3;
    float ncsq=(a3*a3*p2+2.0f*a3*b3*xyc+b3*b3*y2c)*d3*d3;
    { float nn=fsqrt(ncsq+1e-15f);
      if(nn>PMX){ float sc=PMX*frcp(nn); nc0*=sc; nc1_*=sc; ncsq*=sc*sc; } }
    float nl=fsqrt(ncsq+1e-15f);
    float gL=fatanh(nl)*frcp(nl);
    float T0=ftanh(gL*nc0), T1=ftanh(gL*nc1_);
    float tsq=wred(T0*T0+T1*T1); float nT=fsqrt(tsq+1e-15f);
    float wo0=op0*T0, wo1=op1*T1;
    float osq=wred(wo0*wo0+wo1*wo1); float nwo=fsqrt(osq+1e-15f);
    float tH=ftanh(nwo*frcp(nT)*fatanh(nT)); float fH=fminf(tH,PMX)*frcp(nwo);
    *(f32x2*)&out[0*NHS + b128] = (f32x2){fH*wo0, fH*wo1};
    *(f32x2*)&out[1*NHS + b128] = (f32x2){nc0, nc1_};
  }
  // ================= Sphere =================
  {
    float Y[6], I[6];
#pragma unroll
    for(int p=0;p<3;p++){
      f32x2 yv = ldh2(&YS[b384 + 128*p]);
      f32x2 iv = *(const f32x2*)&iou2[b384 + 128*p];
      Y[2*p]=yv[0]; Y[2*p+1]=yv[1]; I[2*p]=iv[0]; I[2*p+1]=iv[1];
    }
    float sy=0,si=0,sx=0;
#pragma unroll
    for(int r=0;r<6;r++){ sy+=Y[r]*Y[r]; si+=I[r]*I[r]; sx+=I[r]*Y[r]; }
    sy=wred(sy); si=wred(si); sx=wred(sx);
    float nY=fsqrt(sy+1e-15f);
    float te=ftan(nY); float fE=te*frcp(nY);
    float y2=fE*fE*sy, x2=si, xy=fE*sx;
    float aa=1.0f-2.0f*xy-y2, bb=1.0f+x2;
    float dd=frcp(safeden(1.0f-2.0f*xy+x2*y2));
    float nio[6];
#pragma unroll
    for(int r=0;r<6;r++) nio[r]=(aa*I[r]+bb*fE*Y[r])*dd;
    float ci=wred(nio[0]*nio[0]+nio[1]*nio[1]); float ni=fsqrt(ci+1e-15f); float gi=fatan(ni)*frcp(ni);
    float ip0=sigm(gi*nio[0]), ip1=sigm(gi*nio[1]);
    float co=wred(nio[2]*nio[2]+nio[3]*nio[3]); float no=fsqrt(co+1e-15f); float go=fatan(no)*frcp(no);
    float op0=sigm(go*nio[2]), op1=sigm(go*nio[3]);
    float cu=wred(nio[4]*nio[4]+nio[5]*nio[5]); float nu=fsqrt(cu+1e-15f); float gu=fatan(nu)*frcp(nu);
    float up0=ftanh(gu*nio[4]), up1=ftanh(gu*nio[5]);
    float usq=wred(up0*up0+up1*up1); float nx=fsqrt(usq+1e-15f);
    float wv0=ip0*up0, wv1=ip1*up1;
    float wsq=wred(wv0*wv0+wv1*wv1); float nwx=fsqrt(wsq+1e-15f);
    float tP=ftan(nwx*frcp(nx)*fatan(nx)); float fP=tP*frcp(nwx);
    float P0=fP*wv0, P1=fP*wv1; float p2=fP*fP*wsq;
    f32x2 cv = ldh2(&C2v[b128]);
    float ca=cv[0], cb=cv[1];
    float y2c=c2n2[n];
    float xyc=wred(P0*ca+P1*cb);
    float a3=1.0f-2.0f*xyc-y2c, b3=1.0f+p2;
    float d3=frcp(safeden(1.0f-2.0f*xyc+p2*y2c));
    float nc0=(a3*P0+b3*ca)*d3, nc1_=(a3*P1+b3*cb)*d3;
    float ncsq=(a3*a3*p2+2.0f*a3*b3*xyc+b3*b3*y2c)*d3*d3;
    float nl=fsqrt(ncsq+1e-15f);
    float gL=fatan(nl)*frcp(nl);
    float T0=ftanh(gL*nc0), T1=ftanh(gL*nc1_);
    float tsq=wred(T0*T0+T1*T1); float nT=fsqrt(tsq+1e-15f);
    float wo0=op0*T0, wo1=op1*T1;
    float osq=wred(wo0*wo0+wo1*wo1); float nwo=fsqrt(osq+1e-15f);
    float tH=ftan(nwo*frcp(nT)*fatan(nT)); float fH=tH*frcp(nwo);
    *(f32x2*)&out[2*NHS + b128] = (f32x2){fH*wo0, fH*wo1};
    *(f32x2*)&out[3*NHS + b128] = (f32x2){nc0, nc1_};
  }
  // ================= Euclid =================
  {
    float Y[6], I[6];
#pragma unroll
    for(int p=0;p<3;p++){
      f32x2 yv = ldh2(&YE[b384 + 128*p]);
      f32x2 iv = *(const f32x2*)&iou3[b384 + 128*p];
      Y[2*p]=yv[0]; Y[2*p+1]=yv[1]; I[2*p]=iv[0]; I[2*p+1]=iv[1];
    }
    float n0=I[0]+Y[0], n1=I[1]+Y[1];
    float n2=I[2]+Y[2], n3=I[3]+Y[3];
    float n4=I[4]+Y[4], n5=I[5]+Y[5];
    float ie0=sigm(n0), ie1=sigm(n1);
    float oe0=sigm(n2), oe1=sigm(n3);
    float ue0=ftanh(n4), ue1=ftanh(n5);
    f32x2 cv = ldh2(&C3v[b128]);
    float ca=cv[0], cb=cv[1];
    float nc0=ie0*ue0+ca, nc1_=ie1*ue1+cb;
    *(f32x2*)&out[4*NHS + b128] = (f32x2){oe0*ftanh(nc0), oe1*ftanh(nc1_)};
    *(f32x2*)&out[5*NHS + b128] = (f32x2){nc0, nc1_};
  }
}

extern "C" void kernel_launch(void* const* d_in, const int* in_sizes, int n_in,
                              void* d_out, int out_size, void* d_ws, size_t ws_size,
                              hipStream_t stream)
{
  const float* x     = (const float*)d_in[0];
  const float* h1    = (const float*)d_in[1];
  const float* c1    = (const float*)d_in[2];
  const float* h2    = (const float*)d_in[3];
  const float* c2    = (const float*)d_in[4];
  const float* h3    = (const float*)d_in[5];
  const float* c3    = (const float*)d_in[6];
  const float* del_t = (const float*)d_in[7];
  const float* iou1  = (const float*)d_in[8];
  const float* iou2  = (const float*)d_in[9];
  const float* iou3  = (const float*)d_in[10];
  const float* Wq_w  = (const float*)d_in[11];
  const float* Wq_b  = (const float*)d_in[12];
  const float* Wc_w  = (const float*)d_in[13];
  const float* Wc_b  = (const float*)d_in[14];
  const float* Uf_w  = (const float*)d_in[15];
  const float* Uf_b  = (const float*)d_in[16];
  const float* Up_w  = (const float*)d_in[17];
  const float* Up_b  = (const float*)d_in[18];
  const float* Uiou_w= (const float*)d_in[19];
  const float* Uiou_b= (const float*)d_in[20];
  const float* dsc   = (const float*)d_in[21];
  const int*   nbr   = (const int*)d_in[22];
  float* out = (float*)d_out;
  float* ws  = (float*)d_ws;

  // fused weight f16-convert + row pre-transforms
  k_pre<<<2160,256,0,stream>>>(x,h1,h2,c1,c2,h3,c3,Wq_w,Wc_w,Uf_w,Up_w,Uiou_w,ws);

  u16* WH = (u16*)(ws + WOFF);
  const u16* Wqh = WH;
  const u16* Wch = WH + 16384;
  const u16* Ufh = WH + 32768;
  const u16* Uph = WH + 49152;
  const u16* UIh = WH + 65536;
#define APLANE(R) ((const u16*)(ws + (size_t)(R)*NHS))

  JobTabM A{};
  A.j[0]  = { APLANE(0), Wqh, Wq_b, (u16*)(ws+18*NHS), 128, P_EXP_P };      // XP
  A.j[1]  = { APLANE(1), Wqh, Wq_b, (u16*)(ws+19*NHS), 128, P_EXP_S };      // XS
  A.j[2]  = { APLANE(2), Wqh, Wq_b, (u16*)(ws+20*NHS), 128, P_ID };         // XE
  A.j[3]  = { APLANE(3), Uph, Up_b, (u16*)(ws+9*NHS),  128, P_SIG_LOG_P };  // S1
  A.j[4]  = { APLANE(4), Uph, Up_b, (u16*)(ws+10*NHS), 128, P_SIG_LOG_S };  // S2
  A.j[5]  = { APLANE(5), Uph, Up_b, (u16*)(ws+11*NHS), 128, P_SIG };        // S3
  A.j[6]  = { APLANE(3), Ufh, Uf_b, (u16*)(ws+12*NHS), 128, P_LOGSIG_P };   // F1
  A.j[7]  = { APLANE(4), Ufh, Uf_b, (u16*)(ws+13*NHS), 128, P_LOGSIG_S };   // F2
  A.j[8]  = { APLANE(5), Ufh, Uf_b, (u16*)(ws+14*NHS), 128, P_SIG };        // F3
  A.j[9]  = { APLANE(6), Wch, Wc_b, (u16*)(ws+15*NHS), 128, P_TANH_EXP_P }; // CS1
  A.j[10] = { APLANE(7), Wch, Wc_b, (u16*)(ws+16*NHS), 128, P_TANH_EXP_S }; // CS2
  A.j[11] = { APLANE(8), Wch, Wc_b, (u16*)(ws+17*NHS), 128, P_TANH };       // CS3
  k_gemmM<<<dim3(NNODE/128,12),512,0,stream>>>(A);

  k_phaseB<<<2048,256,0,stream>>>(h1,h2,h3,c1,c2,c3,del_t,dsc,ws);
  k_attn<<<8192,256,0,stream>>>(nbr,ws);

  JobTabM B{};
  for(int ct=0; ct<3; ct++){
    B.j[0*3+ct] = { APLANE(9),  UIh + ct*16384, Uiou_b + ct*128, (u16*)(ws+0*NHS) + ct*128, 384, P_ID };
    B.j[1*3+ct] = { APLANE(10), UIh + ct*16384, Uiou_b + ct*128, (u16*)(ws+3*NHS) + ct*128, 384, P_ID };
    B.j[2*3+ct] = { APLANE(11), UIh + ct*16384, Uiou_b + ct*128, (u16*)(ws+6*NHS) + ct*128, 384, P_ID };
  }
  k_gemmM<<<dim3(NNODE/128,9),512,0,stream>>>(B);

  k_final<<<2048,256,0,stream>>>(iou1,iou2,iou3,ws,out);
}